// Round 1
// baseline (199.931 us; speedup 1.0000x reference)
//
#include <hip/hip_runtime.h>
#include <cstdint>
#include <cstddef>

#define N 1024
#define HN 4
#define FDIM 64
#define KSEL 512
#define FLT_MAX_ 3.402823466e+38f

// ---------------- reduction helpers ----------------
__device__ __forceinline__ float wred_sum(float v){
#pragma unroll
  for(int o=32;o>0;o>>=1) v += __shfl_down(v,o,64);
  return v;
}
__device__ __forceinline__ float bfly_sum(float v){
#pragma unroll
  for(int o=1;o<64;o<<=1) v += __shfl_xor(v,o,64);
  return v;
}
__device__ __forceinline__ float bfly_max(float v){
#pragma unroll
  for(int o=1;o<64;o<<=1) v = fmaxf(v,__shfl_xor(v,o,64));
  return v;
}
__device__ __forceinline__ int bfly_sumi(int v){
#pragma unroll
  for(int o=1;o<64;o<<=1) v += __shfl_xor(v,o,64);
  return v;
}
__device__ __forceinline__ float bred_sum(float v, float* scr){
  int t=threadIdx.x;
  v = wred_sum(v);
  __syncthreads();
  if((t&63)==0) scr[t>>6]=v;
  __syncthreads();
  return (scr[0]+scr[1])+(scr[2]+scr[3]);
}

// ---------------- K1: fused gemm + pack_adj + mask zero + feats min/max ----------
__global__ __launch_bounds__(256) void stage1(const float* __restrict__ x,
                                              const float* __restrict__ W_l,
                                              const float* __restrict__ W_r,
                                              const int* __restrict__ adj,
                                              const float* __restrict__ feats,
                                              float* __restrict__ g_l,
                                              float* __restrict__ g_r,
                                              unsigned* __restrict__ adjbit,
                                              int* __restrict__ masks,
                                              float* __restrict__ pmin_f,
                                              float* __restrict__ pmax_f){
  int bx = blockIdx.x, t = threadIdx.x;
  if(bx < 512){
    const float* __restrict__ W = (bx >= 256) ? W_r : W_l;
    float* __restrict__ g = (bx >= 256) ? g_r : g_l;
    int i0 = (bx & 255)*4;
    float acc[4] = {0.f,0.f,0.f,0.f};
#pragma unroll 8
    for(int k=0;k<256;k++){
      float w = W[(size_t)k*256 + t];
#pragma unroll
      for(int r=0;r<4;r++) acc[r] = fmaf(x[(size_t)(i0+r)*256 + k], w, acc[r]);
    }
#pragma unroll
    for(int r=0;r<4;r++) g[(size_t)(i0+r)*256 + t] = acc[r];
  } else if(bx < 1536){
    int i = bx - 512, w = t>>6, lane = t&63;
    if(i < 32) masks[i*256 + t] = 0;
#pragma unroll
    for(int it=0; it<4; it++){
      int j = w*256 + it*64 + lane;
      int v = adj[(size_t)i*N + j];
      unsigned long long mb = __ballot(v > 0);
      if(lane == 0){
        adjbit[i*32 + w*8 + it*2]     = (unsigned)mb;
        adjbit[i*32 + w*8 + it*2 + 1] = (unsigned)(mb >> 32);
      }
    }
  } else {
    int chunk = bx - 1536;
    if(t < 128){
      float lo = FLT_MAX_, hi = -FLT_MAX_;
      int r0 = chunk*64;
      for(int r=0;r<64;r++){
        float v = feats[(size_t)(r0+r)*128 + t];
        lo = fminf(lo,v); hi = fmaxf(hi,v);
      }
      pmin_f[chunk*128+t]=lo; pmax_f[chunk*128+t]=hi;
    }
  }
}

// ---------------- K2: fused compute_e (+eT transpose) + g_r min/max + nf norms ----
__global__ __launch_bounds__(256) void stage2(const float* __restrict__ g_l,
                                              const float* __restrict__ g_r,
                                              const float* __restrict__ attn_w,
                                              const float* __restrict__ feats,
                                              const float* __restrict__ pmin_f, const float* __restrict__ pmax_f,
                                              float* __restrict__ pmin_g, float* __restrict__ pmax_g,
                                              float* __restrict__ nf,
                                              float* __restrict__ e,
                                              float* __restrict__ eT){
  __shared__ __align__(16) float smem[2*64*68 + 128];
  int bx = blockIdx.x, t = threadIdx.x;
  if(bx < 1024){
    float* grs = smem;                 // [64][68]
    float* gls = smem + 64*68;         // [64][68]
    float* aw  = smem + 2*64*68;       // [64]
    float* aw2 = aw + 64;              // [64]
    int h = bx >> 8, i0 = ((bx>>4)&15)*64, j0 = (bx&15)*64;
    if(t < 64){ float w = attn_w[t]; aw[t]=w; aw2[t]=0.2f*w; }
#pragma unroll
    for(int k=0;k<16;k++){
      int idx = t + k*256; int r = idx>>6, f = idx&63;
      grs[r*68+f] = g_r[(size_t)(i0+r)*256 + h*64 + f];
      gls[r*68+f] = g_l[(size_t)(j0+r)*256 + h*64 + f];
    }
    __syncthreads();
    int tj = t&15, ti = t>>4;
    float acc[4][4];
#pragma unroll
    for(int a=0;a<4;a++)
#pragma unroll
      for(int b=0;b<4;b++) acc[a][b]=0.f;
    for(int fc=0; fc<64; fc+=4){
      float4 wv  = *(float4*)&aw[fc];
      float4 wv2 = *(float4*)&aw2[fc];
      float4 ga4[4], gb4[4];
#pragma unroll
      for(int a=0;a<4;a++) ga4[a] = *(float4*)&grs[(ti*4+a)*68+fc];
#pragma unroll
      for(int b=0;b<4;b++) gb4[b] = *(float4*)&gls[(tj+16*b)*68+fc];
#pragma unroll
      for(int a=0;a<4;a++)
#pragma unroll
        for(int b=0;b<4;b++){
          float s0 = ga4[a].x + gb4[b].x;
          float s1 = ga4[a].y + gb4[b].y;
          float s2 = ga4[a].z + gb4[b].z;
          float s3 = ga4[a].w + gb4[b].w;
          acc[a][b] = fmaf(s0, (s0>=0.f)?wv.x:wv2.x, acc[a][b]);
          acc[a][b] = fmaf(s1, (s1>=0.f)?wv.y:wv2.y, acc[a][b]);
          acc[a][b] = fmaf(s2, (s2>=0.f)?wv.z:wv2.z, acc[a][b]);
          acc[a][b] = fmaf(s3, (s3>=0.f)?wv.w:wv2.w, acc[a][b]);
        }
    }
#pragma unroll
    for(int a=0;a<4;a++)
#pragma unroll
      for(int b=0;b<4;b++){
        int i = i0 + ti*4 + a, j = j0 + tj + 16*b;
        e[((size_t)h*N + i)*N + j] = acc[a][b];
      }
    // transposed copy eT[h][j][i] via LDS (reuse grs/gls region)
    __syncthreads();                        // all reads of grs/gls done
    float* esT = smem;                      // [64][68]
#pragma unroll
    for(int a=0;a<4;a++)
#pragma unroll
      for(int b=0;b<4;b++)
        esT[(tj + 16*b)*68 + ti*4 + a] = acc[a][b];
    __syncthreads();
#pragma unroll
    for(int k=0;k<4;k++){
      int jl = (t>>4) + 16*k, ilx = (t&15)*4;
      *(float4*)(eT + ((size_t)h*N + j0 + jl)*N + i0 + ilx) = *(float4*)&esT[jl*68 + ilx];
    }
  } else if(bx < 1040){
    int chunk = bx - 1024;
    float lo = FLT_MAX_, hi = -FLT_MAX_;
    int r0 = chunk*64;
    for(int r=0;r<64;r++){
      float v = g_r[(size_t)(r0+r)*256 + t];
      lo = fminf(lo,v); hi = fmaxf(hi,v);
    }
    pmin_g[chunk*256+t]=lo; pmax_g[chunk*256+t]=hi;
  } else {
    int i = bx - 1040;
    float* scr = smem;
    float u = 0.f;
    if(t < 128){
      float lo = FLT_MAX_, hi = -FLT_MAX_;
#pragma unroll
      for(int k=0;k<16;k++){
        lo = fminf(lo, pmin_f[k*128+t]);
        hi = fmaxf(hi, pmax_f[k*128+t]);
      }
      float d = hi - lo;
      float v = feats[(size_t)i*128 + t];
      u = (d==0.f) ? 0.f : (v - lo)/d;
    }
    float tot = bred_sum(u*u, scr);
    if(t==0) nf[i] = sqrtf(tot);
  }
}

// ---------------- K3: row stats — wave/(h,row), inline ng, zero barriers ----------
__global__ __launch_bounds__(256) void row_stats(const float* __restrict__ e,
                                                 const unsigned* __restrict__ adjbit,
                                                 const float* __restrict__ nf,
                                                 const float* __restrict__ g_r,
                                                 const float* __restrict__ pmin_g, const float* __restrict__ pmax_g,
                                                 float* __restrict__ ng,
                                                 float* __restrict__ mlA, float* __restrict__ islA,
                                                 float* __restrict__ moA, float* __restrict__ isoA,
                                                 float* __restrict__ maA, float* __restrict__ isaA,
                                                 float* __restrict__ mgA, float* __restrict__ sgA){
  int i = blockIdx.x, t = threadIdx.x, h = t>>6, lane = t&63;
  float glo = FLT_MAX_, ghi = -FLT_MAX_;
#pragma unroll
  for(int k=0;k<16;k++){
    glo = fminf(glo, pmin_g[k*256 + h*64 + lane]);
    ghi = fmaxf(ghi, pmax_g[k*256 + h*64 + lane]);
  }
  float dg = ghi - glo;
  float ug = (g_r[(size_t)i*256 + h*64 + lane] - glo)/dg;   // no guard (matches ref)
  float ngv = sqrtf(bfly_sum(ug*ug));
  if(lane==0) ng[h*N + i] = ngv;

  size_t base = ((size_t)h*N + i)*N;
  float er[16], nfr[16];
  unsigned nib[4];
#pragma unroll
  for(int c=0;c<4;c++){
    float4 e4 = *(const float4*)(e  + base + c*256 + lane*4);
    float4 n4 = *(const float4*)(nf + c*256 + lane*4);
    er[c*4+0]=e4.x; er[c*4+1]=e4.y; er[c*4+2]=e4.z; er[c*4+3]=e4.w;
    nfr[c*4+0]=n4.x; nfr[c*4+1]=n4.y; nfr[c*4+2]=n4.z; nfr[c*4+3]=n4.w;
    nib[c] = (adjbit[i*32 + c*8 + (lane>>3)] >> ((lane&7)*4)) & 0xFu;
  }
  float ml=-FLT_MAX_, mo=-FLT_MAX_, ma=-FLT_MAX_;
#pragma unroll
  for(int c=0;c<4;c++)
#pragma unroll
    for(int k=0;k<4;k++){
      int q = c*4+k;
      float ev = er[q];
      mo = fmaxf(mo, ev);
      if((nib[c]>>k)&1) ml = fmaxf(ml, ev);
      ma = fmaxf(ma, fabsf(nfr[q]-ngv));
    }
  ml = bfly_max(ml); mo = bfly_max(mo); ma = bfly_max(ma);
  float sl=0.f, so=0.f, sa=0.f;
#pragma unroll
  for(int c=0;c<4;c++)
#pragma unroll
    for(int k=0;k<4;k++){
      int q = c*4+k;
      float ev = er[q];
      so += __expf(ev-mo);
      if((nib[c]>>k)&1) sl += __expf(ev-ml);
      sa += __expf(fabsf(nfr[q]-ngv)-ma);
    }
  sl = bfly_sum(sl); so = bfly_sum(so); sa = bfly_sum(sa);
  float isl = 1.f/sl, iso = 1.f/so, isa = 1.f/sa;
  float gg[16];
  float mg = -FLT_MAX_;
#pragma unroll
  for(int q=0;q<16;q++){
    float ev = er[q];
    float omega = __expf(ev-mo)*iso;
    float alpha = __expf(fabsf(nfr[q]-ngv)-ma)*isa;
    float g = 0.5f*(omega + 1.f - alpha);
    gg[q] = g;
    mg = fmaxf(mg, g);
  }
  mg = bfly_max(mg);
  float sg = 0.f;
#pragma unroll
  for(int q=0;q<16;q++) sg += __expf((gg[q]-mg)/1e-3f);
  sg = bfly_sum(sg);
  if(lane==0){
    mlA[h*N+i]=ml; islA[h*N+i]=isl;
    moA[h*N+i]=mo; isoA[h*N+i]=iso;
    maA[h*N+i]=ma; isaA[h*N+i]=isa;
    mgA[h*N+i]=mg; sgA[h*N+i]=sg;
  }
}

// ---------------- top-512 radix select over one column (wave-synchronous) --------
__device__ __forceinline__ void select_top(const unsigned* ur, int* hw,
                                           int* __restrict__ mask, int base, int lane){
  int np = 0;
#pragma unroll
  for(int q=0;q<16;q++) np += (ur[q] != 0u) ? 1 : 0;
  int cnt_pos = bfly_sumi(np);

  unsigned T; int tneed; int tiecnt = -1;
  if(cnt_pos < KSEL){
    T = 0u; tneed = KSEL - cnt_pos;       // threshold exactly 0; zeros fill by index
  } else {
    unsigned prefix = 0; int kth = KSEL;
#pragma unroll
    for(int b=3;b>=0;b--){
      *(int4*)&hw[lane*4] = make_int4(0,0,0,0);
#pragma unroll
      for(int q=0;q<16;q++){
        unsigned u = ur[q];
        bool act = (b==3) || ((u >> (8*(b+1))) == prefix);
        if(act){
          int bucket = (u >> (8*b)) & 0xFF;
          unsigned long long mball = __ballot(true);
          int lead = __ffsll(mball) - 1;
          int maj = __shfl(bucket, lead, 64);
          if(bucket == maj){
            int cnt = (int)__popcll(__ballot(true));
            if(lane == lead) atomicAdd(&hw[maj], cnt);
          } else {
            atomicAdd(&hw[bucket], 1);
          }
        }
      }
      int4 hv = *(int4*)&hw[lane*4];      // lane owns bins 4l..4l+3
      int s = hv.x+hv.y+hv.z+hv.w;
      int P = s;
#pragma unroll
      for(int off=1; off<64; off<<=1){
        int q2 = __shfl_up(P, off, 64);
        if(lane >= off) P += q2;
      }
      int total = __shfl(P, 63, 64);
      int suffChunk  = total - (P - s);
      int suffChunkN = total - P;
      bool cross = (suffChunk >= kth) && (suffChunkN < kth);
      int selb=0, newk=0, tcnt=0;
      if(cross){
        int s3 = suffChunkN + hv.w;
        int s2 = s3 + hv.z;
        int s1 = s2 + hv.y;
        if(s3 >= kth){ selb=4*lane+3; newk = kth - suffChunkN; tcnt=hv.w; }
        else if(s2 >= kth){ selb=4*lane+2; newk = kth - s3; tcnt=hv.z; }
        else if(s1 >= kth){ selb=4*lane+1; newk = kth - s2; tcnt=hv.y; }
        else { selb=4*lane; newk = kth - s1; tcnt=hv.x; }
      }
      unsigned long long cm = __ballot(cross);
      int csrc = __ffsll(cm) - 1;
      selb   = __shfl(selb, csrc, 64);
      kth    = __shfl(newk, csrc, 64);
      tiecnt = __shfl(tcnt, csrc, 64);
      prefix = (prefix << 8) | (unsigned)selb;
    }
    T = prefix; tneed = kth;
  }

  if(tiecnt == tneed){
#pragma unroll
    for(int c=0;c<4;c++)
#pragma unroll
      for(int k2=0;k2<4;k2++){
        int i = c*256 + lane*4 + k2;
        if(ur[c*4+k2] >= T) mask[base + i] = 1;
      }
  } else {
    int run_base = 0;
#pragma unroll
    for(int c=0;c<4;c++){
      int tc=0;
#pragma unroll
      for(int k2=0;k2<4;k2++) tc += (ur[c*4+k2]==T)?1:0;
      int pc = tc;
#pragma unroll
      for(int off=1; off<64; off<<=1){
        int q2 = __shfl_up(pc, off, 64);
        if(lane >= off) pc += q2;
      }
      int ctot = __shfl(pc, 63, 64);
      int run = run_base + pc - tc;
#pragma unroll
      for(int k2=0;k2<4;k2++){
        int i = c*256 + lane*4 + k2;
        unsigned u = ur[c*4+k2];
        bool sel = (u > T) || (u == T && run < tneed);
        run += (u==T)?1:0;
        if(sel) mask[base + i] = 1;
      }
      run_base += ctot;
    }
  }
}

// ---------------- K5: fused dual top-512 — recompute a1 & gamma from eT ----------
__global__ __launch_bounds__(256) void colselect7(const float* __restrict__ eT,
                                                  const unsigned* __restrict__ adjbit,
                                                  const float* __restrict__ nf,
                                                  const float* __restrict__ mlA, const float* __restrict__ islA,
                                                  const float* __restrict__ moA, const float* __restrict__ isoA,
                                                  const float* __restrict__ maA, const float* __restrict__ isaA,
                                                  const float* __restrict__ ngA,
                                                  int* __restrict__ mask_l,
                                                  int* __restrict__ mask_g){
  __shared__ __align__(16) int hist[4][256];
  int t = threadIdx.x, w = t>>6, lane = t&63;
  int col = blockIdx.x*4 + w;             // h*N + j, 0..4095
  int h = col >> 10, jc = col & 1023;
  const float* __restrict__ src = eT + (size_t)col * (size_t)N;

  float ev[16];
  unsigned abits = 0;
  int wo = jc >> 5; unsigned bm = 1u << (jc & 31);
#pragma unroll
  for(int c=0;c<4;c++){
    float4 e4 = ((const float4*)src)[c*64 + lane];
    ev[c*4+0]=e4.x; ev[c*4+1]=e4.y; ev[c*4+2]=e4.z; ev[c*4+3]=e4.w;
#pragma unroll
    for(int k=0;k<4;k++){
      int i = c*256 + lane*4 + k;
      abits |= (adjbit[i*32 + wo] & bm) ? (1u << (c*4+k)) : 0u;
    }
  }
  unsigned ur[16];
  // ---- a1 column: adj ? exp(e-ml)*isl : 0 ----
#pragma unroll
  for(int c=0;c<4;c++){
    int ib = (h<<10) + c*256 + lane*4;
    float4 ml4 = *(const float4*)(mlA+ib);
    float4 il4 = *(const float4*)(islA+ib);
    float mlv[4] = {ml4.x,ml4.y,ml4.z,ml4.w};
    float ilv[4] = {il4.x,il4.y,il4.z,il4.w};
#pragma unroll
    for(int k=0;k<4;k++){
      float a = ((abits>>(c*4+k))&1u) ? __expf(ev[c*4+k]-mlv[k])*ilv[k] : 0.f;
      ur[c*4+k] = __float_as_uint(a);
    }
  }
  select_top(ur, hist[w], mask_l, h<<10, lane);
  // ---- gamma column: 0.5*(omega + 1 - alpha) ----
  float nfv = nf[jc];
#pragma unroll
  for(int c=0;c<4;c++){
    int ib = (h<<10) + c*256 + lane*4;
    float4 mo4 = *(const float4*)(moA+ib);
    float4 io4 = *(const float4*)(isoA+ib);
    float4 ma4 = *(const float4*)(maA+ib);
    float4 ia4 = *(const float4*)(isaA+ib);
    float4 ng4 = *(const float4*)(ngA+ib);
    float mov[4]={mo4.x,mo4.y,mo4.z,mo4.w}, iov[4]={io4.x,io4.y,io4.z,io4.w};
    float mav[4]={ma4.x,ma4.y,ma4.z,ma4.w}, iav[4]={ia4.x,ia4.y,ia4.z,ia4.w};
    float ngv[4]={ng4.x,ng4.y,ng4.z,ng4.w};
#pragma unroll
    for(int k=0;k<4;k++){
      float omega = __expf(ev[c*4+k]-mov[k])*iov[k];
      float alpha = __expf(fabsf(nfv-ngv[k])-mav[k])*iav[k];
      float g = 0.5f*(omega + 1.f - alpha);
      ur[c*4+k] = __float_as_uint(g);
    }
  }
  select_top(ur, hist[w], mask_g, h<<10, lane);
}

// ---------------- K6: attn matmuls — stage from eT with a1/p recompute ----------
// grid (32, HN, 8): i0 = bx*32, h, j0 = s*128. Stats live in registers (i fixed/thread).
__global__ __launch_bounds__(256) void attn_mm2(const float* __restrict__ eT,
                                                const float* __restrict__ g_r,
                                                const unsigned* __restrict__ adjbit,
                                                const float* __restrict__ nf,
                                                const float* __restrict__ mlA, const float* __restrict__ islA,
                                                const float* __restrict__ moA, const float* __restrict__ isoA,
                                                const float* __restrict__ maA, const float* __restrict__ isaA,
                                                const float* __restrict__ ngA,
                                                const float* __restrict__ mgA, const float* __restrict__ sgA,
                                                const int* __restrict__ mask_g,
                                                float* __restrict__ partL,
                                                float* __restrict__ partG){
  __shared__ __align__(16) float a_t[2][32][36];
  __shared__ __align__(16) float p_t[2][32][36];
  __shared__ __align__(16) float b_s[2][32][68];
  int i0 = blockIdx.x*32, h = blockIdx.y, s = blockIdx.z, j0 = s*128;
  int t = threadIdx.x;
  int il = t & 31, jq = t >> 5;          // staging: one i, four j per sub-tile
  int gi = h*N + i0 + il;
  float ml_r = mlA[gi], il_r = islA[gi];
  float mo_r = moA[gi], io_r = isoA[gi];
  float ma_r = maA[gi], ia_r = isaA[gi];
  float ng_r = ngA[gi];
  float mg_r = mgA[gi], isg_r = 1.f/sgA[gi];
  int   mgf_r = mask_g[gi];
  int fq = t & 15, iq = t >> 4;
  int jb2a = t>>4, d4a = t&15;
  int idxb = t + 256, jb2b = idxb>>4, d4b = idxb&15;

  float e0,e1,e2,e3; unsigned aw; float4 nf4, vb0, vb1;
  // prologue: load sub 0
  {
    int jb = j0;
    size_t ebase = ((size_t)h*N + jb + jq*4)*(size_t)N + i0 + il;
    e0 = eT[ebase]; e1 = eT[ebase+N]; e2 = eT[ebase+2*N]; e3 = eT[ebase+3*N];
    aw = adjbit[(size_t)(i0+il)*32 + s*4 + 0];
    nf4 = *(const float4*)(nf + jb + jq*4);
    vb0 = *(const float4*)(g_r + (size_t)(jb+jb2a)*256 + h*64 + d4a*4);
    vb1 = *(const float4*)(g_r + (size_t)(jb+jb2b)*256 + h*64 + d4b*4);
  }
  // compute + write buf 0
  {
    const float inv = 1.f/1024.f;
    float evs[4] = {e0,e1,e2,e3};
    float nfsv[4] = {nf4.x,nf4.y,nf4.z,nf4.w};
#pragma unroll
    for(int c=0;c<4;c++){
      int jl = jq*4 + c;                 // j local within 32-tile == bit index
      float a = ((aw >> jl) & 1u) ? __expf(evs[c]-ml_r)*il_r : 0.f;
      float omega = __expf(evs[c]-mo_r)*io_r;
      float alpha = __expf(fabsf(nfsv[c]-ng_r)-ma_r)*ia_r;
      float g = 0.5f*(omega + 1.f - alpha);
      float p = mgf_r ? __expf((g-mg_r)/1e-3f)*isg_r : inv;
      a_t[0][jl][il] = a;
      p_t[0][jl][il] = p;
    }
    *(float4*)&b_s[0][jb2a][d4a*4] = vb0;
    *(float4*)&b_s[0][jb2b][d4b*4] = vb1;
  }
  float4 accL[2], accG[2];
#pragma unroll
  for(int r=0;r<2;r++){ accL[r]=make_float4(0,0,0,0); accG[r]=make_float4(0,0,0,0); }

  for(int sub=0; sub<4; sub++){
    int cur = sub & 1;
    __syncthreads();                       // buf[cur] ready; buf[1-cur] free
    if(sub < 3){                           // issue next tile's loads (overlap compute)
      int jb = j0 + (sub+1)*32;
      size_t ebase = ((size_t)h*N + jb + jq*4)*(size_t)N + i0 + il;
      e0 = eT[ebase]; e1 = eT[ebase+N]; e2 = eT[ebase+2*N]; e3 = eT[ebase+3*N];
      aw = adjbit[(size_t)(i0+il)*32 + s*4 + sub + 1];
      nf4 = *(const float4*)(nf + jb + jq*4);
      vb0 = *(const float4*)(g_r + (size_t)(jb+jb2a)*256 + h*64 + d4a*4);
      vb1 = *(const float4*)(g_r + (size_t)(jb+jb2b)*256 + h*64 + d4b*4);
    }
#pragma unroll 8
    for(int j=0;j<32;j++){
      float4 bv = *(float4*)&b_s[cur][j][fq*4];
      float2 av = *(float2*)&a_t[cur][j][iq*2];
      float2 pv = *(float2*)&p_t[cur][j][iq*2];
      accL[0].x = fmaf(av.x, bv.x, accL[0].x); accL[0].y = fmaf(av.x, bv.y, accL[0].y);
      accL[0].z = fmaf(av.x, bv.z, accL[0].z); accL[0].w = fmaf(av.x, bv.w, accL[0].w);
      accL[1].x = fmaf(av.y, bv.x, accL[1].x); accL[1].y = fmaf(av.y, bv.y, accL[1].y);
      accL[1].z = fmaf(av.y, bv.z, accL[1].z); accL[1].w = fmaf(av.y, bv.w, accL[1].w);
      accG[0].x = fmaf(pv.x, bv.x, accG[0].x); accG[0].y = fmaf(pv.x, bv.y, accG[0].y);
      accG[0].z = fmaf(pv.x, bv.z, accG[0].z); accG[0].w = fmaf(pv.x, bv.w, accG[0].w);
      accG[1].x = fmaf(pv.y, bv.x, accG[1].x); accG[1].y = fmaf(pv.y, bv.y, accG[1].y);
      accG[1].z = fmaf(pv.y, bv.z, accG[1].z); accG[1].w = fmaf(pv.y, bv.w, accG[1].w);
    }
    if(sub < 3){                           // write next buffer (barrier above ensures free)
      int nxt = 1 - cur;
      const float inv = 1.f/1024.f;
      float evs[4] = {e0,e1,e2,e3};
      float nfsv[4] = {nf4.x,nf4.y,nf4.z,nf4.w};
#pragma unroll
      for(int c=0;c<4;c++){
        int jl = jq*4 + c;
        float a = ((aw >> jl) & 1u) ? __expf(evs[c]-ml_r)*il_r : 0.f;
        float omega = __expf(evs[c]-mo_r)*io_r;
        float alpha = __expf(fabsf(nfsv[c]-ng_r)-ma_r)*ia_r;
        float g = 0.5f*(omega + 1.f - alpha);
        float p = mgf_r ? __expf((g-mg_r)/1e-3f)*isg_r : inv;
        a_t[nxt][jl][il] = a;
        p_t[nxt][jl][il] = p;
      }
      *(float4*)&b_s[nxt][jb2a][d4a*4] = vb0;
      *(float4*)&b_s[nxt][jb2b][d4b*4] = vb1;
    }
  }
#pragma unroll
  for(int r=0;r<2;r++){
    int i = i0 + iq*2 + r;
    size_t o = ((size_t)s*N + i)*256 + h*64 + fq*4;
    *(float4*)&partL[o] = accL[r];
    *(float4*)&partG[o] = accG[r];
  }
}

// ---------------- K7: reduce partials + delta-gate epilogue ----------------
__global__ __launch_bounds__(256) void epilogue(const float* __restrict__ partL,
                                                const float* __restrict__ partG,
                                                const int* __restrict__ mask_l,
                                                const float* __restrict__ W_delta,
                                                const float* __restrict__ b_delta,
                                                float* __restrict__ out){
  __shared__ float cat[4][128];
  __shared__ float inter_s[4][64];
  int i = blockIdx.x, t = threadIdx.x;
  int h = t>>6, f = t&63;
  float sl = 0.f, sg = 0.f;
#pragma unroll
  for(int s2=0;s2<8;s2++){
    size_t o = ((size_t)s2*N + i)*256 + h*64 + f;
    sl += partL[o];
    sg += partG[o];
  }
  if(!mask_l[h*N + i]) sl = 0.f;
  cat[h][f]      = sl;
  cat[h][64 + f] = sg;
  __syncthreads();
  float d = b_delta[f];
  for(int c=0;c<128;c++) d = fmaf(cat[h][c], W_delta[(size_t)c*64 + f], d);
  d = (d >= 0.f) ? d : 0.2f*d;
  inter_s[h][f] = d;
  __syncthreads();
  float m = inter_s[0][f];
#pragma unroll
  for(int hh=1;hh<4;hh++) m = fmaxf(m, inter_s[hh][f]);
  float ssum = 0.f;
#pragma unroll
  for(int hh=0;hh<4;hh++) ssum += __expf(inter_s[hh][f]-m);
  float delta = __expf(d - m)/ssum;
  out[(size_t)i*256 + h*64 + f] = delta*sl + (1.f - delta)*sg;
}

// ---------------- launch ----------------
extern "C" void kernel_launch(void* const* d_in, const int* in_sizes, int n_in,
                              void* d_out, int out_size, void* d_ws, size_t ws_size,
                              hipStream_t stream) {
  const float* feats  = (const float*)d_in[0];
  const float* x      = (const float*)d_in[1];
  const int*   adj    = (const int*)  d_in[2];
  const float* W_l    = (const float*)d_in[3];
  const float* W_r    = (const float*)d_in[4];
  const float* attn_w = (const float*)d_in[5];
  const float* W_delta= (const float*)d_in[6];
  const float* b_delta= (const float*)d_in[7];
  float* out = (float*)d_out;

  float* ws = (float*)d_ws;
  size_t off = 0;
  float* g_l   = ws+off; off += (size_t)N*256;
  float* g_r   = ws+off; off += (size_t)N*256;
  float* e     = ws+off; off += (size_t)HN*N*N;      // raw scores, row-major
  float* eT    = ws+off; off += (size_t)HN*N*N;      // raw scores, transposed
  float* partL = ws+off; off += (size_t)8*N*256;     // per-s partials
  float* partG = ws+off; off += (size_t)8*N*256;
  float* pmin_f= ws+off; off += 16*128;
  float* pmax_f= ws+off; off += 16*128;
  float* pmin_g= ws+off; off += 16*256;
  float* pmax_g= ws+off; off += 16*256;
  float* nf    = ws+off; off += N;
  float* ng    = ws+off; off += (size_t)HN*N;
  float* mlA   = ws+off; off += (size_t)HN*N;
  float* islA  = ws+off; off += (size_t)HN*N;
  float* moA   = ws+off; off += (size_t)HN*N;
  float* isoA  = ws+off; off += (size_t)HN*N;
  float* maA   = ws+off; off += (size_t)HN*N;
  float* isaA  = ws+off; off += (size_t)HN*N;
  float* mgA   = ws+off; off += (size_t)HN*N;
  float* sgA   = ws+off; off += (size_t)HN*N;
  int* mask_l  = (int*)(ws+off); off += (size_t)HN*N;   // mask_l & mask_g contiguous
  int* mask_g  = (int*)(ws+off); off += (size_t)HN*N;
  unsigned* adjbit = (unsigned*)(ws+off); off += (size_t)N*32;

  stage1<<<1552, 256, 0, stream>>>(x, W_l, W_r, adj, feats, g_l, g_r, adjbit, mask_l, pmin_f, pmax_f);

  stage2<<<2064, 256, 0, stream>>>(g_l, g_r, attn_w, feats, pmin_f, pmax_f,
                                   pmin_g, pmax_g, nf, e, eT);

  row_stats<<<N, 256, 0, stream>>>(e, adjbit, nf, g_r, pmin_g, pmax_g, ng,
                                   mlA, islA, moA, isoA, maA, isaA, mgA, sgA);

  colselect7<<<1024, 256, 0, stream>>>(eT, adjbit, nf, mlA, islA, moA, isoA,
                                       maA, isaA, ng, mask_l, mask_g);

  attn_mm2<<<dim3(32,HN,8), 256, 0, stream>>>(eT, g_r, adjbit, nf,
                                              mlA, islA, moA, isoA, maA, isaA, ng,
                                              mgA, sgA, mask_g, partL, partG);

  epilogue<<<N, 256, 0, stream>>>(partL, partG, mask_l, W_delta, b_delta, out);
}

// Round 3
// 199.055 us; speedup vs baseline: 1.0044x; 1.0044x over previous
//
#include <hip/hip_runtime.h>
#include <cstdint>
#include <cstddef>

#define N 1024
#define HN 4
#define FDIM 64
#define KSEL 512
#define FLT_MAX_ 3.402823466e+38f

// ---------------- reduction helpers ----------------
__device__ __forceinline__ float wred_sum(float v){
#pragma unroll
  for(int o=32;o>0;o>>=1) v += __shfl_down(v,o,64);
  return v;
}
__device__ __forceinline__ float bfly_sum(float v){
#pragma unroll
  for(int o=1;o<64;o<<=1) v += __shfl_xor(v,o,64);
  return v;
}
__device__ __forceinline__ float bfly_max(float v){
#pragma unroll
  for(int o=1;o<64;o<<=1) v = fmaxf(v,__shfl_xor(v,o,64));
  return v;
}
__device__ __forceinline__ int bfly_sumi(int v){
#pragma unroll
  for(int o=1;o<64;o<<=1) v += __shfl_xor(v,o,64);
  return v;
}
__device__ __forceinline__ float bred_sum(float v, float* scr){
  int t=threadIdx.x;
  v = wred_sum(v);
  __syncthreads();
  if((t&63)==0) scr[t>>6]=v;
  __syncthreads();
  return (scr[0]+scr[1])+(scr[2]+scr[3]);
}

// ---------------- K1: fused gemm + pack_adj + mask zero + feats min/max ----------
__global__ __launch_bounds__(256) void stage1(const float* __restrict__ x,
                                              const float* __restrict__ W_l,
                                              const float* __restrict__ W_r,
                                              const int* __restrict__ adj,
                                              const float* __restrict__ feats,
                                              float* __restrict__ g_l,
                                              float* __restrict__ g_r,
                                              unsigned* __restrict__ adjbit,
                                              int* __restrict__ masks,
                                              float* __restrict__ pmin_f,
                                              float* __restrict__ pmax_f){
  int bx = blockIdx.x, t = threadIdx.x;
  if(bx < 512){
    const float* __restrict__ W = (bx >= 256) ? W_r : W_l;
    float* __restrict__ g = (bx >= 256) ? g_r : g_l;
    int i0 = (bx & 255)*4;
    float acc[4] = {0.f,0.f,0.f,0.f};
#pragma unroll 8
    for(int k=0;k<256;k++){
      float w = W[(size_t)k*256 + t];
#pragma unroll
      for(int r=0;r<4;r++) acc[r] = fmaf(x[(size_t)(i0+r)*256 + k], w, acc[r]);
    }
#pragma unroll
    for(int r=0;r<4;r++) g[(size_t)(i0+r)*256 + t] = acc[r];
  } else if(bx < 1536){
    int i = bx - 512, w = t>>6, lane = t&63;
    if(i < 32) masks[i*256 + t] = 0;
#pragma unroll
    for(int it=0; it<4; it++){
      int j = w*256 + it*64 + lane;
      int v = adj[(size_t)i*N + j];
      unsigned long long mb = __ballot(v > 0);
      if(lane == 0){
        adjbit[i*32 + w*8 + it*2]     = (unsigned)mb;
        adjbit[i*32 + w*8 + it*2 + 1] = (unsigned)(mb >> 32);
      }
    }
  } else {
    int chunk = bx - 1536;
    if(t < 128){
      float lo = FLT_MAX_, hi = -FLT_MAX_;
      int r0 = chunk*64;
      for(int r=0;r<64;r++){
        float v = feats[(size_t)(r0+r)*128 + t];
        lo = fminf(lo,v); hi = fmaxf(hi,v);
      }
      pmin_f[chunk*128+t]=lo; pmax_f[chunk*128+t]=hi;
    }
  }
}

// ---------------- K2: fused compute_e (+eT transpose) + g_r min/max + nf norms ----
__global__ __launch_bounds__(256) void stage2(const float* __restrict__ g_l,
                                              const float* __restrict__ g_r,
                                              const float* __restrict__ attn_w,
                                              const float* __restrict__ feats,
                                              const float* __restrict__ pmin_f, const float* __restrict__ pmax_f,
                                              float* __restrict__ pmin_g, float* __restrict__ pmax_g,
                                              float* __restrict__ nf,
                                              float* __restrict__ e,
                                              float* __restrict__ eT){
  __shared__ __align__(16) float smem[2*64*68 + 128];
  int bx = blockIdx.x, t = threadIdx.x;
  if(bx < 1024){
    float* grs = smem;                 // [64][68]
    float* gls = smem + 64*68;         // [64][68]
    float* aw  = smem + 2*64*68;       // [64]
    float* aw2 = aw + 64;              // [64]
    int h = bx >> 8, i0 = ((bx>>4)&15)*64, j0 = (bx&15)*64;
    if(t < 64){ float w = attn_w[t]; aw[t]=w; aw2[t]=0.2f*w; }
#pragma unroll
    for(int k=0;k<16;k++){
      int idx = t + k*256; int r = idx>>6, f = idx&63;
      grs[r*68+f] = g_r[(size_t)(i0+r)*256 + h*64 + f];
      gls[r*68+f] = g_l[(size_t)(j0+r)*256 + h*64 + f];
    }
    __syncthreads();
    int tj = t&15, ti = t>>4;
    float acc[4][4];
#pragma unroll
    for(int a=0;a<4;a++)
#pragma unroll
      for(int b=0;b<4;b++) acc[a][b]=0.f;
    for(int fc=0; fc<64; fc+=4){
      float4 wv  = *(float4*)&aw[fc];
      float4 wv2 = *(float4*)&aw2[fc];
      float4 ga4[4], gb4[4];
#pragma unroll
      for(int a=0;a<4;a++) ga4[a] = *(float4*)&grs[(ti*4+a)*68+fc];
#pragma unroll
      for(int b=0;b<4;b++) gb4[b] = *(float4*)&gls[(tj+16*b)*68+fc];
#pragma unroll
      for(int a=0;a<4;a++)
#pragma unroll
        for(int b=0;b<4;b++){
          float s0 = ga4[a].x + gb4[b].x;
          float s1 = ga4[a].y + gb4[b].y;
          float s2 = ga4[a].z + gb4[b].z;
          float s3 = ga4[a].w + gb4[b].w;
          acc[a][b] = fmaf(s0, (s0>=0.f)?wv.x:wv2.x, acc[a][b]);
          acc[a][b] = fmaf(s1, (s1>=0.f)?wv.y:wv2.y, acc[a][b]);
          acc[a][b] = fmaf(s2, (s2>=0.f)?wv.z:wv2.z, acc[a][b]);
          acc[a][b] = fmaf(s3, (s3>=0.f)?wv.w:wv2.w, acc[a][b]);
        }
    }
#pragma unroll
    for(int a=0;a<4;a++)
#pragma unroll
      for(int b=0;b<4;b++){
        int i = i0 + ti*4 + a, j = j0 + tj + 16*b;
        e[((size_t)h*N + i)*N + j] = acc[a][b];
      }
    // transposed copy eT[h][j][i] via LDS (reuse grs/gls region)
    __syncthreads();                        // all reads of grs/gls done
    float* esT = smem;                      // [64][68]
#pragma unroll
    for(int a=0;a<4;a++)
#pragma unroll
      for(int b=0;b<4;b++)
        esT[(tj + 16*b)*68 + ti*4 + a] = acc[a][b];
    __syncthreads();
#pragma unroll
    for(int k=0;k<4;k++){
      int jl = (t>>4) + 16*k, ilx = (t&15)*4;
      *(float4*)(eT + ((size_t)h*N + j0 + jl)*N + i0 + ilx) = *(float4*)&esT[jl*68 + ilx];
    }
  } else if(bx < 1040){
    int chunk = bx - 1024;
    float lo = FLT_MAX_, hi = -FLT_MAX_;
    int r0 = chunk*64;
    for(int r=0;r<64;r++){
      float v = g_r[(size_t)(r0+r)*256 + t];
      lo = fminf(lo,v); hi = fmaxf(hi,v);
    }
    pmin_g[chunk*256+t]=lo; pmax_g[chunk*256+t]=hi;
  } else {
    int i = bx - 1040;
    float* scr = smem;
    float u = 0.f;
    if(t < 128){
      float lo = FLT_MAX_, hi = -FLT_MAX_;
#pragma unroll
      for(int k=0;k<16;k++){
        lo = fminf(lo, pmin_f[k*128+t]);
        hi = fmaxf(hi, pmax_f[k*128+t]);
      }
      float d = hi - lo;
      float v = feats[(size_t)i*128 + t];
      u = (d==0.f) ? 0.f : (v - lo)/d;
    }
    float tot = bred_sum(u*u, scr);
    if(t==0) nf[i] = sqrtf(tot);
  }
}

// ---------------- K3: row stats — wave/(h,row), inline ng, zero barriers ----------
__global__ __launch_bounds__(256) void row_stats(const float* __restrict__ e,
                                                 const unsigned* __restrict__ adjbit,
                                                 const float* __restrict__ nf,
                                                 const float* __restrict__ g_r,
                                                 const float* __restrict__ pmin_g, const float* __restrict__ pmax_g,
                                                 float* __restrict__ ng,
                                                 float* __restrict__ mlA, float* __restrict__ islA,
                                                 float* __restrict__ moA, float* __restrict__ isoA,
                                                 float* __restrict__ maA, float* __restrict__ isaA,
                                                 float* __restrict__ mgA, float* __restrict__ sgA){
  int i = blockIdx.x, t = threadIdx.x, h = t>>6, lane = t&63;
  float glo = FLT_MAX_, ghi = -FLT_MAX_;
#pragma unroll
  for(int k=0;k<16;k++){
    glo = fminf(glo, pmin_g[k*256 + h*64 + lane]);
    ghi = fmaxf(ghi, pmax_g[k*256 + h*64 + lane]);
  }
  float dg = ghi - glo;
  float ug = (g_r[(size_t)i*256 + h*64 + lane] - glo)/dg;   // no guard (matches ref)
  float ngv = sqrtf(bfly_sum(ug*ug));
  if(lane==0) ng[h*N + i] = ngv;

  size_t base = ((size_t)h*N + i)*N;
  float er[16], nfr[16];
  unsigned nib[4];
#pragma unroll
  for(int c=0;c<4;c++){
    float4 e4 = *(const float4*)(e  + base + c*256 + lane*4);
    float4 n4 = *(const float4*)(nf + c*256 + lane*4);
    er[c*4+0]=e4.x; er[c*4+1]=e4.y; er[c*4+2]=e4.z; er[c*4+3]=e4.w;
    nfr[c*4+0]=n4.x; nfr[c*4+1]=n4.y; nfr[c*4+2]=n4.z; nfr[c*4+3]=n4.w;
    nib[c] = (adjbit[i*32 + c*8 + (lane>>3)] >> ((lane&7)*4)) & 0xFu;
  }
  float ml=-FLT_MAX_, mo=-FLT_MAX_, ma=-FLT_MAX_;
#pragma unroll
  for(int c=0;c<4;c++)
#pragma unroll
    for(int k=0;k<4;k++){
      int q = c*4+k;
      float ev = er[q];
      mo = fmaxf(mo, ev);
      if((nib[c]>>k)&1) ml = fmaxf(ml, ev);
      ma = fmaxf(ma, fabsf(nfr[q]-ngv));
    }
  ml = bfly_max(ml); mo = bfly_max(mo); ma = bfly_max(ma);
  float sl=0.f, so=0.f, sa=0.f;
#pragma unroll
  for(int c=0;c<4;c++)
#pragma unroll
    for(int k=0;k<4;k++){
      int q = c*4+k;
      float ev = er[q];
      so += __expf(ev-mo);
      if((nib[c]>>k)&1) sl += __expf(ev-ml);
      sa += __expf(fabsf(nfr[q]-ngv)-ma);
    }
  sl = bfly_sum(sl); so = bfly_sum(so); sa = bfly_sum(sa);
  float isl = 1.f/sl, iso = 1.f/so, isa = 1.f/sa;
  float gg[16];
  float mg = -FLT_MAX_;
#pragma unroll
  for(int q=0;q<16;q++){
    float ev = er[q];
    float omega = __expf(ev-mo)*iso;
    float alpha = __expf(fabsf(nfr[q]-ngv)-ma)*isa;
    float g = 0.5f*(omega + 1.f - alpha);
    gg[q] = g;
    mg = fmaxf(mg, g);
  }
  mg = bfly_max(mg);
  float sg = 0.f;
#pragma unroll
  for(int q=0;q<16;q++) sg += __expf((gg[q]-mg)/1e-3f);
  sg = bfly_sum(sg);
  if(lane==0){
    mlA[h*N+i]=ml; islA[h*N+i]=isl;
    moA[h*N+i]=mo; isoA[h*N+i]=iso;
    maA[h*N+i]=ma; isaA[h*N+i]=isa;
    mgA[h*N+i]=mg; sgA[h*N+i]=sg;
  }
}

// ---------------- mask application with exact tie semantics (index order) --------
__device__ __forceinline__ void apply_mask(const unsigned* ur, unsigned T, int tneed, int EQ,
                                           int* __restrict__ mask, int base, int lane){
  if(EQ == tneed){
#pragma unroll
    for(int c=0;c<4;c++)
#pragma unroll
      for(int k2=0;k2<4;k2++){
        int i = c*256 + lane*4 + k2;
        if(ur[c*4+k2] >= T) mask[base + i] = 1;
      }
  } else {
    int run_base = 0;
#pragma unroll
    for(int c=0;c<4;c++){
      int tc=0;
#pragma unroll
      for(int k2=0;k2<4;k2++) tc += (ur[c*4+k2]==T)?1:0;
      int pc = tc;
#pragma unroll
      for(int off=1; off<64; off<<=1){
        int q2 = __shfl_up(pc, off, 64);
        if(lane >= off) pc += q2;
      }
      int ctot = __shfl(pc, 63, 64);
      int run = run_base + pc - tc;
#pragma unroll
      for(int k2=0;k2<4;k2++){
        int i = c*256 + lane*4 + k2;
        unsigned u = ur[c*4+k2];
        bool sel = (u > T) || (u == T && run < tneed);
        run += (u==T)?1:0;
        if(sel) mask[base + i] = 1;
      }
      run_base += ctot;
    }
  }
}

// ---------------- K5: dual top-512 — bitwise kth-largest, register-only ----------
// grid 2048: gcol = bx*4+w in [0,8192). z=gcol>>12 picks a1 (0) vs gamma (1).
// One select per wave; values recomputed from eT + row stats (no LDS, no atomics).
__global__ __launch_bounds__(256) void colselect8(const float* __restrict__ eT,
                                                  const unsigned* __restrict__ adjbit,
                                                  const float* __restrict__ nf,
                                                  const float* __restrict__ mlA, const float* __restrict__ islA,
                                                  const float* __restrict__ moA, const float* __restrict__ isoA,
                                                  const float* __restrict__ maA, const float* __restrict__ isaA,
                                                  const float* __restrict__ ngA,
                                                  int* __restrict__ mask_l,
                                                  int* __restrict__ mask_g){
  int t = threadIdx.x, w = t>>6, lane = t&63;
  int gcol = blockIdx.x*4 + w;            // 0..8191
  int z  = gcol >> 12;                    // 0: a1 select, 1: gamma select
  int hj = gcol & 4095;
  int h  = hj >> 10, jc = hj & 1023;
  const float* __restrict__ src = eT + (size_t)hj * (size_t)N;

  float ev[16];
#pragma unroll
  for(int c=0;c<4;c++){
    float4 e4 = ((const float4*)src)[c*64 + lane];
    ev[c*4+0]=e4.x; ev[c*4+1]=e4.y; ev[c*4+2]=e4.z; ev[c*4+3]=e4.w;
  }
  unsigned ur[16];
  if(z == 0){
    // a1 column: adj ? exp(e-ml)*isl : 0
    int wo = jc >> 5; unsigned bm = 1u << (jc & 31);
#pragma unroll
    for(int c=0;c<4;c++){
      int ib = (h<<10) + c*256 + lane*4;
      float4 ml4 = *(const float4*)(mlA+ib);
      float4 il4 = *(const float4*)(islA+ib);
      float mlv[4] = {ml4.x,ml4.y,ml4.z,ml4.w};
      float ilv[4] = {il4.x,il4.y,il4.z,il4.w};
#pragma unroll
      for(int k=0;k<4;k++){
        int i = c*256 + lane*4 + k;
        float a = (adjbit[i*32 + wo] & bm) ? __expf(ev[c*4+k]-mlv[k])*ilv[k] : 0.f;
        ur[c*4+k] = __float_as_uint(a);
      }
    }
  } else {
    // gamma column: 0.5*(omega + 1 - alpha)
    float nfv = nf[jc];
#pragma unroll
    for(int c=0;c<4;c++){
      int ib = (h<<10) + c*256 + lane*4;
      float4 mo4 = *(const float4*)(moA+ib);
      float4 io4 = *(const float4*)(isoA+ib);
      float4 ma4 = *(const float4*)(maA+ib);
      float4 ia4 = *(const float4*)(isaA+ib);
      float4 ng4 = *(const float4*)(ngA+ib);
      float mov[4]={mo4.x,mo4.y,mo4.z,mo4.w}, iov[4]={io4.x,io4.y,io4.z,io4.w};
      float mav[4]={ma4.x,ma4.y,ma4.z,ma4.w}, iav[4]={ia4.x,ia4.y,ia4.z,ia4.w};
      float ngv[4]={ng4.x,ng4.y,ng4.z,ng4.w};
#pragma unroll
      for(int k=0;k<4;k++){
        float omega = __expf(ev[c*4+k]-mov[k])*iov[k];
        float alpha = __expf(fabsf(nfv-ngv[k])-mav[k])*iav[k];
        float g = 0.5f*(omega + 1.f - alpha);
        ur[c*4+k] = __float_as_uint(g);
      }
    }
  }

  // bitwise kth-largest (values are non-negative floats -> uint order-isomorphic;
  // sign bit always 0, so 31-bit search). Also subsumes the "fewer than KSEL
  // positives" case: prefix stays 0 -> T=0, tneed = KSEL - count(v>0).
  unsigned prefix = 0u;
  for(int b=30; b>=0; b--){
    unsigned cand = prefix | (1u<<b);
    int c = 0;
#pragma unroll
    for(int q=0;q<16;q++) c += (ur[q] >= cand) ? 1 : 0;
    c = bfly_sumi(c);
    if(c >= KSEL) prefix = cand;
  }
  unsigned T = prefix;
  int pk = 0;
#pragma unroll
  for(int q=0;q<16;q++) pk += (ur[q] > T) ? 2048 : ((ur[q]==T) ? 1 : 0);
  pk = bfly_sumi(pk);
  int GT = pk >> 11, EQ = pk & 2047;
  int tneed = KSEL - GT;

  int* __restrict__ mask = z ? mask_g : mask_l;
  apply_mask(ur, T, tneed, EQ, mask, h<<10, lane);
}

// ---------------- K6: attn matmuls — stage from eT with a1/p recompute ----------
// grid (32, HN, 8): i0 = bx*32, h, j0 = s*128. Stats live in registers (i fixed/thread).
__global__ __launch_bounds__(256) void attn_mm2(const float* __restrict__ eT,
                                                const float* __restrict__ g_r,
                                                const unsigned* __restrict__ adjbit,
                                                const float* __restrict__ nf,
                                                const float* __restrict__ mlA, const float* __restrict__ islA,
                                                const float* __restrict__ moA, const float* __restrict__ isoA,
                                                const float* __restrict__ maA, const float* __restrict__ isaA,
                                                const float* __restrict__ ngA,
                                                const float* __restrict__ mgA, const float* __restrict__ sgA,
                                                const int* __restrict__ mask_g,
                                                float* __restrict__ partL,
                                                float* __restrict__ partG){
  __shared__ __align__(16) float a_t[2][32][36];
  __shared__ __align__(16) float p_t[2][32][36];
  __shared__ __align__(16) float b_s[2][32][68];
  int i0 = blockIdx.x*32, h = blockIdx.y, s = blockIdx.z, j0 = s*128;
  int t = threadIdx.x;
  int il = t & 31, jq = t >> 5;          // staging: one i, four j per sub-tile
  int gi = h*N + i0 + il;
  float ml_r = mlA[gi], il_r = islA[gi];
  float mo_r = moA[gi], io_r = isoA[gi];
  float ma_r = maA[gi], ia_r = isaA[gi];
  float ng_r = ngA[gi];
  float mg_r = mgA[gi], isg_r = 1.f/sgA[gi];
  int   mgf_r = mask_g[gi];
  int fq = t & 15, iq = t >> 4;
  int jb2a = t>>4, d4a = t&15;
  int idxb = t + 256, jb2b = idxb>>4, d4b = idxb&15;

  float e0,e1,e2,e3; unsigned aw; float4 nf4, vb0, vb1;
  // prologue: load sub 0
  {
    int jb = j0;
    size_t ebase = ((size_t)h*N + jb + jq*4)*(size_t)N + i0 + il;
    e0 = eT[ebase]; e1 = eT[ebase+N]; e2 = eT[ebase+2*N]; e3 = eT[ebase+3*N];
    aw = adjbit[(size_t)(i0+il)*32 + s*4 + 0];
    nf4 = *(const float4*)(nf + jb + jq*4);
    vb0 = *(const float4*)(g_r + (size_t)(jb+jb2a)*256 + h*64 + d4a*4);
    vb1 = *(const float4*)(g_r + (size_t)(jb+jb2b)*256 + h*64 + d4b*4);
  }
  // compute + write buf 0
  {
    const float inv = 1.f/1024.f;
    float evs[4] = {e0,e1,e2,e3};
    float nfsv[4] = {nf4.x,nf4.y,nf4.z,nf4.w};
#pragma unroll
    for(int c=0;c<4;c++){
      int jl = jq*4 + c;                 // j local within 32-tile == bit index
      float a = ((aw >> jl) & 1u) ? __expf(evs[c]-ml_r)*il_r : 0.f;
      float omega = __expf(evs[c]-mo_r)*io_r;
      float alpha = __expf(fabsf(nfsv[c]-ng_r)-ma_r)*ia_r;
      float g = 0.5f*(omega + 1.f - alpha);
      float p = mgf_r ? __expf((g-mg_r)/1e-3f)*isg_r : inv;
      a_t[0][jl][il] = a;
      p_t[0][jl][il] = p;
    }
    *(float4*)&b_s[0][jb2a][d4a*4] = vb0;
    *(float4*)&b_s[0][jb2b][d4b*4] = vb1;
  }
  float4 accL[2], accG[2];
#pragma unroll
  for(int r=0;r<2;r++){ accL[r]=make_float4(0,0,0,0); accG[r]=make_float4(0,0,0,0); }

  for(int sub=0; sub<4; sub++){
    int cur = sub & 1;
    __syncthreads();                       // buf[cur] ready; buf[1-cur] free
    if(sub < 3){                           // issue next tile's loads (overlap compute)
      int jb = j0 + (sub+1)*32;
      size_t ebase = ((size_t)h*N + jb + jq*4)*(size_t)N + i0 + il;
      e0 = eT[ebase]; e1 = eT[ebase+N]; e2 = eT[ebase+2*N]; e3 = eT[ebase+3*N];
      aw = adjbit[(size_t)(i0+il)*32 + s*4 + sub + 1];
      nf4 = *(const float4*)(nf + jb + jq*4);
      vb0 = *(const float4*)(g_r + (size_t)(jb+jb2a)*256 + h*64 + d4a*4);
      vb1 = *(const float4*)(g_r + (size_t)(jb+jb2b)*256 + h*64 + d4b*4);
    }
#pragma unroll 8
    for(int j=0;j<32;j++){
      float4 bv = *(float4*)&b_s[cur][j][fq*4];
      float2 av = *(float2*)&a_t[cur][j][iq*2];
      float2 pv = *(float2*)&p_t[cur][j][iq*2];
      accL[0].x = fmaf(av.x, bv.x, accL[0].x); accL[0].y = fmaf(av.x, bv.y, accL[0].y);
      accL[0].z = fmaf(av.x, bv.z, accL[0].z); accL[0].w = fmaf(av.x, bv.w, accL[0].w);
      accL[1].x = fmaf(av.y, bv.x, accL[1].x); accL[1].y = fmaf(av.y, bv.y, accL[1].y);
      accL[1].z = fmaf(av.y, bv.z, accL[1].z); accL[1].w = fmaf(av.y, bv.w, accL[1].w);
      accG[0].x = fmaf(pv.x, bv.x, accG[0].x); accG[0].y = fmaf(pv.x, bv.y, accG[0].y);
      accG[0].z = fmaf(pv.x, bv.z, accG[0].z); accG[0].w = fmaf(pv.x, bv.w, accG[0].w);
      accG[1].x = fmaf(pv.y, bv.x, accG[1].x); accG[1].y = fmaf(pv.y, bv.y, accG[1].y);
      accG[1].z = fmaf(pv.y, bv.z, accG[1].z); accG[1].w = fmaf(pv.y, bv.w, accG[1].w);
    }
    if(sub < 3){                           // write next buffer (barrier above ensures free)
      int nxt = 1 - cur;
      const float inv = 1.f/1024.f;
      float evs[4] = {e0,e1,e2,e3};
      float nfsv[4] = {nf4.x,nf4.y,nf4.z,nf4.w};
#pragma unroll
      for(int c=0;c<4;c++){
        int jl = jq*4 + c;
        float a = ((aw >> jl) & 1u) ? __expf(evs[c]-ml_r)*il_r : 0.f;
        float omega = __expf(evs[c]-mo_r)*io_r;
        float alpha = __expf(fabsf(nfsv[c]-ng_r)-ma_r)*ia_r;
        float g = 0.5f*(omega + 1.f - alpha);
        float p = mgf_r ? __expf((g-mg_r)/1e-3f)*isg_r : inv;
        a_t[nxt][jl][il] = a;
        p_t[nxt][jl][il] = p;
      }
      *(float4*)&b_s[nxt][jb2a][d4a*4] = vb0;
      *(float4*)&b_s[nxt][jb2b][d4b*4] = vb1;
    }
  }
#pragma unroll
  for(int r=0;r<2;r++){
    int i = i0 + iq*2 + r;
    size_t o = ((size_t)s*N + i)*256 + h*64 + fq*4;
    *(float4*)&partL[o] = accL[r];
    *(float4*)&partG[o] = accG[r];
  }
}

// ---------------- K7: reduce partials + delta-gate epilogue ----------------
__global__ __launch_bounds__(256) void epilogue(const float* __restrict__ partL,
                                                const float* __restrict__ partG,
                                                const int* __restrict__ mask_l,
                                                const float* __restrict__ W_delta,
                                                const float* __restrict__ b_delta,
                                                float* __restrict__ out){
  __shared__ float cat[4][128];
  __shared__ float inter_s[4][64];
  int i = blockIdx.x, t = threadIdx.x;
  int h = t>>6, f = t&63;
  float sl = 0.f, sg = 0.f;
#pragma unroll
  for(int s2=0;s2<8;s2++){
    size_t o = ((size_t)s2*N + i)*256 + h*64 + f;
    sl += partL[o];
    sg += partG[o];
  }
  if(!mask_l[h*N + i]) sl = 0.f;
  cat[h][f]      = sl;
  cat[h][64 + f] = sg;
  __syncthreads();
  float d = b_delta[f];
  for(int c=0;c<128;c++) d = fmaf(cat[h][c], W_delta[(size_t)c*64 + f], d);
  d = (d >= 0.f) ? d : 0.2f*d;
  inter_s[h][f] = d;
  __syncthreads();
  float m = inter_s[0][f];
#pragma unroll
  for(int hh=1;hh<4;hh++) m = fmaxf(m, inter_s[hh][f]);
  float ssum = 0.f;
#pragma unroll
  for(int hh=0;hh<4;hh++) ssum += __expf(inter_s[hh][f]-m);
  float delta = __expf(d - m)/ssum;
  out[(size_t)i*256 + h*64 + f] = delta*sl + (1.f - delta)*sg;
}

// ---------------- launch ----------------
extern "C" void kernel_launch(void* const* d_in, const int* in_sizes, int n_in,
                              void* d_out, int out_size, void* d_ws, size_t ws_size,
                              hipStream_t stream) {
  const float* feats  = (const float*)d_in[0];
  const float* x      = (const float*)d_in[1];
  const int*   adj    = (const int*)  d_in[2];
  const float* W_l    = (const float*)d_in[3];
  const float* W_r    = (const float*)d_in[4];
  const float* attn_w = (const float*)d_in[5];
  const float* W_delta= (const float*)d_in[6];
  const float* b_delta= (const float*)d_in[7];
  float* out = (float*)d_out;

  float* ws = (float*)d_ws;
  size_t off = 0;
  float* g_l   = ws+off; off += (size_t)N*256;
  float* g_r   = ws+off; off += (size_t)N*256;
  float* e     = ws+off; off += (size_t)HN*N*N;      // raw scores, row-major
  float* eT    = ws+off; off += (size_t)HN*N*N;      // raw scores, transposed
  float* partL = ws+off; off += (size_t)8*N*256;     // per-s partials
  float* partG = ws+off; off += (size_t)8*N*256;
  float* pmin_f= ws+off; off += 16*128;
  float* pmax_f= ws+off; off += 16*128;
  float* pmin_g= ws+off; off += 16*256;
  float* pmax_g= ws+off; off += 16*256;
  float* nf    = ws+off; off += N;
  float* ng    = ws+off; off += (size_t)HN*N;
  float* mlA   = ws+off; off += (size_t)HN*N;
  float* islA  = ws+off; off += (size_t)HN*N;
  float* moA   = ws+off; off += (size_t)HN*N;
  float* isoA  = ws+off; off += (size_t)HN*N;
  float* maA   = ws+off; off += (size_t)HN*N;
  float* isaA  = ws+off; off += (size_t)HN*N;
  float* mgA   = ws+off; off += (size_t)HN*N;
  float* sgA   = ws+off; off += (size_t)HN*N;
  int* mask_l  = (int*)(ws+off); off += (size_t)HN*N;   // mask_l & mask_g contiguous
  int* mask_g  = (int*)(ws+off); off += (size_t)HN*N;
  unsigned* adjbit = (unsigned*)(ws+off); off += (size_t)N*32;

  stage1<<<1552, 256, 0, stream>>>(x, W_l, W_r, adj, feats, g_l, g_r, adjbit, mask_l, pmin_f, pmax_f);

  stage2<<<2064, 256, 0, stream>>>(g_l, g_r, attn_w, feats, pmin_f, pmax_f,
                                   pmin_g, pmax_g, nf, e, eT);

  row_stats<<<N, 256, 0, stream>>>(e, adjbit, nf, g_r, pmin_g, pmax_g, ng,
                                   mlA, islA, moA, isoA, maA, isaA, mgA, sgA);

  colselect8<<<2048, 256, 0, stream>>>(eT, adjbit, nf, mlA, islA, moA, isoA,
                                       maA, isaA, ng, mask_l, mask_g);

  attn_mm2<<<dim3(32,HN,8), 256, 0, stream>>>(eT, g_r, adjbit, nf,
                                              mlA, islA, moA, isoA, maA, isaA, ng,
                                              mgA, sgA, mask_g, partL, partG);

  epilogue<<<N, 256, 0, stream>>>(partL, partG, mask_l, W_delta, b_delta, out);
}

// Round 4
// 193.942 us; speedup vs baseline: 1.0309x; 1.0264x over previous
//
#include <hip/hip_runtime.h>
#include <cstdint>
#include <cstddef>

#define N 1024
#define HN 4
#define FDIM 64
#define KSEL 512
#define FLT_MAX_ 3.402823466e+38f

// ---------------- reduction helpers ----------------
__device__ __forceinline__ float wred_sum(float v){
#pragma unroll
  for(int o=32;o>0;o>>=1) v += __shfl_down(v,o,64);
  return v;
}
__device__ __forceinline__ float bfly_sum(float v){
#pragma unroll
  for(int o=1;o<64;o<<=1) v += __shfl_xor(v,o,64);
  return v;
}
__device__ __forceinline__ float bfly_max(float v){
#pragma unroll
  for(int o=1;o<64;o<<=1) v = fmaxf(v,__shfl_xor(v,o,64));
  return v;
}
__device__ __forceinline__ int bfly_sumi(int v){
#pragma unroll
  for(int o=1;o<64;o<<=1) v += __shfl_xor(v,o,64);
  return v;
}
__device__ __forceinline__ float bred_sum(float v, float* scr){
  int t=threadIdx.x;
  v = wred_sum(v);
  __syncthreads();
  if((t&63)==0) scr[t>>6]=v;
  __syncthreads();
  return (scr[0]+scr[1])+(scr[2]+scr[3]);
}

// ---------------- K1: fused gemm + pack_adj + mask zero + feats min/max ----------
__global__ __launch_bounds__(256) void stage1(const float* __restrict__ x,
                                              const float* __restrict__ W_l,
                                              const float* __restrict__ W_r,
                                              const int* __restrict__ adj,
                                              const float* __restrict__ feats,
                                              float* __restrict__ g_l,
                                              float* __restrict__ g_r,
                                              unsigned* __restrict__ adjbit,
                                              int* __restrict__ masks,
                                              float* __restrict__ pmin_f,
                                              float* __restrict__ pmax_f){
  int bx = blockIdx.x, t = threadIdx.x;
  if(bx < 512){
    const float* __restrict__ W = (bx >= 256) ? W_r : W_l;
    float* __restrict__ g = (bx >= 256) ? g_r : g_l;
    int i0 = (bx & 255)*4;
    float acc[4] = {0.f,0.f,0.f,0.f};
#pragma unroll 8
    for(int k=0;k<256;k++){
      float w = W[(size_t)k*256 + t];
#pragma unroll
      for(int r=0;r<4;r++) acc[r] = fmaf(x[(size_t)(i0+r)*256 + k], w, acc[r]);
    }
#pragma unroll
    for(int r=0;r<4;r++) g[(size_t)(i0+r)*256 + t] = acc[r];
  } else if(bx < 1536){
    int i = bx - 512, w = t>>6, lane = t&63;
    if(i < 32) masks[i*256 + t] = 0;
#pragma unroll
    for(int it=0; it<4; it++){
      int j = w*256 + it*64 + lane;
      int v = adj[(size_t)i*N + j];
      unsigned long long mb = __ballot(v > 0);
      if(lane == 0){
        adjbit[i*32 + w*8 + it*2]     = (unsigned)mb;
        adjbit[i*32 + w*8 + it*2 + 1] = (unsigned)(mb >> 32);
      }
    }
  } else {
    int chunk = bx - 1536;
    if(t < 128){
      float lo = FLT_MAX_, hi = -FLT_MAX_;
      int r0 = chunk*64;
      for(int r=0;r<64;r++){
        float v = feats[(size_t)(r0+r)*128 + t];
        lo = fminf(lo,v); hi = fmaxf(hi,v);
      }
      pmin_f[chunk*128+t]=lo; pmax_f[chunk*128+t]=hi;
    }
  }
}

// ---------------- K2: fused compute_e (+eT transpose) + g_r min/max + nf norms ----
__global__ __launch_bounds__(256) void stage2(const float* __restrict__ g_l,
                                              const float* __restrict__ g_r,
                                              const float* __restrict__ attn_w,
                                              const float* __restrict__ feats,
                                              const float* __restrict__ pmin_f, const float* __restrict__ pmax_f,
                                              float* __restrict__ pmin_g, float* __restrict__ pmax_g,
                                              float* __restrict__ nf,
                                              float* __restrict__ e,
                                              float* __restrict__ eT){
  __shared__ __align__(16) float smem[2*64*68 + 128];
  int bx = blockIdx.x, t = threadIdx.x;
  if(bx < 1024){
    float* grs = smem;                 // [64][68]
    float* gls = smem + 64*68;         // [64][68]
    float* aw  = smem + 2*64*68;       // [64]
    float* aw2 = aw + 64;              // [64]
    int h = bx >> 8, i0 = ((bx>>4)&15)*64, j0 = (bx&15)*64;
    if(t < 64){ float w = attn_w[t]; aw[t]=w; aw2[t]=0.2f*w; }
#pragma unroll
    for(int k=0;k<16;k++){
      int idx = t + k*256; int r = idx>>6, f = idx&63;
      grs[r*68+f] = g_r[(size_t)(i0+r)*256 + h*64 + f];
      gls[r*68+f] = g_l[(size_t)(j0+r)*256 + h*64 + f];
    }
    __syncthreads();
    int tj = t&15, ti = t>>4;
    float acc[4][4];
#pragma unroll
    for(int a=0;a<4;a++)
#pragma unroll
      for(int b=0;b<4;b++) acc[a][b]=0.f;
    for(int fc=0; fc<64; fc+=4){
      float4 wv  = *(float4*)&aw[fc];
      float4 wv2 = *(float4*)&aw2[fc];
      float4 ga4[4], gb4[4];
#pragma unroll
      for(int a=0;a<4;a++) ga4[a] = *(float4*)&grs[(ti*4+a)*68+fc];
#pragma unroll
      for(int b=0;b<4;b++) gb4[b] = *(float4*)&gls[(tj+16*b)*68+fc];
#pragma unroll
      for(int a=0;a<4;a++)
#pragma unroll
        for(int b=0;b<4;b++){
          float s0 = ga4[a].x + gb4[b].x;
          float s1 = ga4[a].y + gb4[b].y;
          float s2 = ga4[a].z + gb4[b].z;
          float s3 = ga4[a].w + gb4[b].w;
          acc[a][b] = fmaf(s0, (s0>=0.f)?wv.x:wv2.x, acc[a][b]);
          acc[a][b] = fmaf(s1, (s1>=0.f)?wv.y:wv2.y, acc[a][b]);
          acc[a][b] = fmaf(s2, (s2>=0.f)?wv.z:wv2.z, acc[a][b]);
          acc[a][b] = fmaf(s3, (s3>=0.f)?wv.w:wv2.w, acc[a][b]);
        }
    }
#pragma unroll
    for(int a=0;a<4;a++)
#pragma unroll
      for(int b=0;b<4;b++){
        int i = i0 + ti*4 + a, j = j0 + tj + 16*b;
        e[((size_t)h*N + i)*N + j] = acc[a][b];
      }
    // transposed copy eT[h][j][i] via LDS (reuse grs/gls region)
    __syncthreads();                        // all reads of grs/gls done
    float* esT = smem;                      // [64][68]
#pragma unroll
    for(int a=0;a<4;a++)
#pragma unroll
      for(int b=0;b<4;b++)
        esT[(tj + 16*b)*68 + ti*4 + a] = acc[a][b];
    __syncthreads();
#pragma unroll
    for(int k=0;k<4;k++){
      int jl = (t>>4) + 16*k, ilx = (t&15)*4;
      *(float4*)(eT + ((size_t)h*N + j0 + jl)*N + i0 + ilx) = *(float4*)&esT[jl*68 + ilx];
    }
  } else if(bx < 1040){
    int chunk = bx - 1024;
    float lo = FLT_MAX_, hi = -FLT_MAX_;
    int r0 = chunk*64;
    for(int r=0;r<64;r++){
      float v = g_r[(size_t)(r0+r)*256 + t];
      lo = fminf(lo,v); hi = fmaxf(hi,v);
    }
    pmin_g[chunk*256+t]=lo; pmax_g[chunk*256+t]=hi;
  } else {
    int i = bx - 1040;
    float* scr = smem;
    float u = 0.f;
    if(t < 128){
      float lo = FLT_MAX_, hi = -FLT_MAX_;
#pragma unroll
      for(int k=0;k<16;k++){
        lo = fminf(lo, pmin_f[k*128+t]);
        hi = fmaxf(hi, pmax_f[k*128+t]);
      }
      float d = hi - lo;
      float v = feats[(size_t)i*128 + t];
      u = (d==0.f) ? 0.f : (v - lo)/d;
    }
    float tot = bred_sum(u*u, scr);
    if(t==0) nf[i] = sqrtf(tot);
  }
}

// ---------------- K3: row stats — wave/(h,row), inline ng, zero barriers ----------
__global__ __launch_bounds__(256) void row_stats(const float* __restrict__ e,
                                                 const unsigned* __restrict__ adjbit,
                                                 const float* __restrict__ nf,
                                                 const float* __restrict__ g_r,
                                                 const float* __restrict__ pmin_g, const float* __restrict__ pmax_g,
                                                 float* __restrict__ ng,
                                                 float* __restrict__ mlA, float* __restrict__ islA,
                                                 float* __restrict__ moA, float* __restrict__ isoA,
                                                 float* __restrict__ maA, float* __restrict__ isaA,
                                                 float* __restrict__ mgA, float* __restrict__ sgA){
  int i = blockIdx.x, t = threadIdx.x, h = t>>6, lane = t&63;
  float glo = FLT_MAX_, ghi = -FLT_MAX_;
#pragma unroll
  for(int k=0;k<16;k++){
    glo = fminf(glo, pmin_g[k*256 + h*64 + lane]);
    ghi = fmaxf(ghi, pmax_g[k*256 + h*64 + lane]);
  }
  float dg = ghi - glo;
  float ug = (g_r[(size_t)i*256 + h*64 + lane] - glo)/dg;   // no guard (matches ref)
  float ngv = sqrtf(bfly_sum(ug*ug));
  if(lane==0) ng[h*N + i] = ngv;

  size_t base = ((size_t)h*N + i)*N;
  float er[16], nfr[16];
  unsigned nib[4];
#pragma unroll
  for(int c=0;c<4;c++){
    float4 e4 = *(const float4*)(e  + base + c*256 + lane*4);
    float4 n4 = *(const float4*)(nf + c*256 + lane*4);
    er[c*4+0]=e4.x; er[c*4+1]=e4.y; er[c*4+2]=e4.z; er[c*4+3]=e4.w;
    nfr[c*4+0]=n4.x; nfr[c*4+1]=n4.y; nfr[c*4+2]=n4.z; nfr[c*4+3]=n4.w;
    nib[c] = (adjbit[i*32 + c*8 + (lane>>3)] >> ((lane&7)*4)) & 0xFu;
  }
  float ml=-FLT_MAX_, mo=-FLT_MAX_, ma=-FLT_MAX_;
#pragma unroll
  for(int c=0;c<4;c++)
#pragma unroll
    for(int k=0;k<4;k++){
      int q = c*4+k;
      float ev = er[q];
      mo = fmaxf(mo, ev);
      if((nib[c]>>k)&1) ml = fmaxf(ml, ev);
      ma = fmaxf(ma, fabsf(nfr[q]-ngv));
    }
  ml = bfly_max(ml); mo = bfly_max(mo); ma = bfly_max(ma);
  float sl=0.f, so=0.f, sa=0.f;
#pragma unroll
  for(int c=0;c<4;c++)
#pragma unroll
    for(int k=0;k<4;k++){
      int q = c*4+k;
      float ev = er[q];
      so += __expf(ev-mo);
      if((nib[c]>>k)&1) sl += __expf(ev-ml);
      sa += __expf(fabsf(nfr[q]-ngv)-ma);
    }
  sl = bfly_sum(sl); so = bfly_sum(so); sa = bfly_sum(sa);
  float isl = 1.f/sl, iso = 1.f/so, isa = 1.f/sa;
  float gg[16];
  float mg = -FLT_MAX_;
#pragma unroll
  for(int q=0;q<16;q++){
    float ev = er[q];
    float omega = __expf(ev-mo)*iso;
    float alpha = __expf(fabsf(nfr[q]-ngv)-ma)*isa;
    float g = 0.5f*(omega + 1.f - alpha);
    gg[q] = g;
    mg = fmaxf(mg, g);
  }
  mg = bfly_max(mg);
  float sg = 0.f;
#pragma unroll
  for(int q=0;q<16;q++) sg += __expf((gg[q]-mg)/1e-3f);
  sg = bfly_sum(sg);
  if(lane==0){
    mlA[h*N+i]=ml; islA[h*N+i]=isl;
    moA[h*N+i]=mo; isoA[h*N+i]=iso;
    maA[h*N+i]=ma; isaA[h*N+i]=isa;
    mgA[h*N+i]=mg; sgA[h*N+i]=sg;
  }
}

// ---------------- mask application with exact tie semantics (index order) --------
__device__ __forceinline__ void apply_mask(const unsigned* ur, unsigned T, int tneed, int EQ,
                                           int* __restrict__ mask, int base, int lane){
  if(EQ == tneed){
#pragma unroll
    for(int c=0;c<4;c++)
#pragma unroll
      for(int k2=0;k2<4;k2++){
        int i = c*256 + lane*4 + k2;
        if(ur[c*4+k2] >= T) mask[base + i] = 1;
      }
  } else {
    int run_base = 0;
#pragma unroll
    for(int c=0;c<4;c++){
      // ballot-based rank among ties for this 256-chunk (index order: lane asc, k asc)
      int tc=0;
      unsigned long long bm[4];
#pragma unroll
      for(int k2=0;k2<4;k2++){
        bm[k2] = __ballot(ur[c*4+k2]==T);
        tc += (ur[c*4+k2]==T)?1:0;
      }
      unsigned long long lower = (lane==0) ? 0ull : (~0ull >> (64-lane));
      int run = run_base;
      // ties at smaller lane (any k), in lane-major order? NOTE: index i = c*256 + lane*4 + k2
      // -> order within chunk is (lane,k2) lexicographic. Count = all k2 of lower lanes + own earlier k2.
#pragma unroll
      for(int k2=0;k2<4;k2++) run += (int)__popcll(bm[k2] & lower);
#pragma unroll
      for(int k2=0;k2<4;k2++){
        int i = c*256 + lane*4 + k2;
        unsigned u = ur[c*4+k2];
        bool sel = (u > T) || (u == T && run < tneed);
        run += (u==T)?1:0;
        if(sel) mask[base + i] = 1;
      }
      int ctot = 0;
#pragma unroll
      for(int k2=0;k2<4;k2++) ctot += (int)__popcll(bm[k2]);
      run_base += ctot;
    }
  }
}

// ---------------- K5: dual top-512 — bitwise kth-largest via ballot counts -------
// grid 2048: gcol = bx*4+w in [0,8192). z=gcol>>12 picks a1 (0) vs gamma (1).
// Wave-count primitive: popcount(ballot(pred)) -> scalar pipe; no shuffles, no LDS.
__global__ __launch_bounds__(256) void colselect9(const float* __restrict__ eT,
                                                  const unsigned* __restrict__ adjbit,
                                                  const float* __restrict__ nf,
                                                  const float* __restrict__ mlA, const float* __restrict__ islA,
                                                  const float* __restrict__ moA, const float* __restrict__ isoA,
                                                  const float* __restrict__ maA, const float* __restrict__ isaA,
                                                  const float* __restrict__ ngA,
                                                  int* __restrict__ mask_l,
                                                  int* __restrict__ mask_g){
  int t = threadIdx.x, w = t>>6, lane = t&63;
  int gcol = blockIdx.x*4 + w;            // 0..8191
  int z  = gcol >> 12;                    // 0: a1 select, 1: gamma select
  int hj = gcol & 4095;
  int h  = hj >> 10, jc = hj & 1023;
  const float* __restrict__ src = eT + (size_t)hj * (size_t)N;

  float ev[16];
#pragma unroll
  for(int c=0;c<4;c++){
    float4 e4 = ((const float4*)src)[c*64 + lane];
    ev[c*4+0]=e4.x; ev[c*4+1]=e4.y; ev[c*4+2]=e4.z; ev[c*4+3]=e4.w;
  }
  unsigned ur[16];
  if(z == 0){
    // a1 column: adj ? exp(e-ml)*isl : 0
    int wo = jc >> 5; unsigned bm = 1u << (jc & 31);
#pragma unroll
    for(int c=0;c<4;c++){
      int ib = (h<<10) + c*256 + lane*4;
      float4 ml4 = *(const float4*)(mlA+ib);
      float4 il4 = *(const float4*)(islA+ib);
      float mlv[4] = {ml4.x,ml4.y,ml4.z,ml4.w};
      float ilv[4] = {il4.x,il4.y,il4.z,il4.w};
#pragma unroll
      for(int k=0;k<4;k++){
        int i = c*256 + lane*4 + k;
        float a = (adjbit[i*32 + wo] & bm) ? __expf(ev[c*4+k]-mlv[k])*ilv[k] : 0.f;
        ur[c*4+k] = __float_as_uint(a);
      }
    }
  } else {
    // gamma column: 0.5*(omega + 1 - alpha)
    float nfv = nf[jc];
#pragma unroll
    for(int c=0;c<4;c++){
      int ib = (h<<10) + c*256 + lane*4;
      float4 mo4 = *(const float4*)(moA+ib);
      float4 io4 = *(const float4*)(isoA+ib);
      float4 ma4 = *(const float4*)(maA+ib);
      float4 ia4 = *(const float4*)(isaA+ib);
      float4 ng4 = *(const float4*)(ngA+ib);
      float mov[4]={mo4.x,mo4.y,mo4.z,mo4.w}, iov[4]={io4.x,io4.y,io4.z,io4.w};
      float mav[4]={ma4.x,ma4.y,ma4.z,ma4.w}, iav[4]={ia4.x,ia4.y,ia4.z,ia4.w};
      float ngv[4]={ng4.x,ng4.y,ng4.z,ng4.w};
#pragma unroll
      for(int k=0;k<4;k++){
        float omega = __expf(ev[c*4+k]-mov[k])*iov[k];
        float alpha = __expf(fabsf(nfv-ngv[k])-mav[k])*iav[k];
        float g = 0.5f*(omega + 1.f - alpha);
        ur[c*4+k] = __float_as_uint(g);
      }
    }
  }

  // bitwise kth-largest; wave count = sum of ballot popcounts (scalar pipe,
  // 16 independent v_cmp per step — no cross-lane latency chain).
  // Values are non-negative floats -> uint order-isomorphic; sign bit 0 -> 31-bit search.
  // Subsumes "fewer than KSEL positives": prefix stays 0 -> T=0, tneed = KSEL - GT.
  unsigned prefix = 0u;
  for(int b=30; b>=0; b--){
    unsigned cand = prefix | (1u<<b);
    int c = 0;
#pragma unroll
    for(int q=0;q<16;q++) c += (int)__popcll(__ballot(ur[q] >= cand));
    prefix = (c >= KSEL) ? cand : prefix;
  }
  unsigned T = prefix;
  int GT = 0, EQ = 0;
#pragma unroll
  for(int q=0;q<16;q++){
    GT += (int)__popcll(__ballot(ur[q] > T));
    EQ += (int)__popcll(__ballot(ur[q] == T));
  }
  int tneed = KSEL - GT;

  int* __restrict__ mask = z ? mask_g : mask_l;
  apply_mask(ur, T, tneed, EQ, mask, h<<10, lane);
}

// ---------------- K6: attn matmuls — stage from eT with a1/p recompute ----------
// grid (32, HN, 8): i0 = bx*32, h, j0 = s*128. Stats live in registers (i fixed/thread).
__global__ __launch_bounds__(256) void attn_mm2(const float* __restrict__ eT,
                                                const float* __restrict__ g_r,
                                                const unsigned* __restrict__ adjbit,
                                                const float* __restrict__ nf,
                                                const float* __restrict__ mlA, const float* __restrict__ islA,
                                                const float* __restrict__ moA, const float* __restrict__ isoA,
                                                const float* __restrict__ maA, const float* __restrict__ isaA,
                                                const float* __restrict__ ngA,
                                                const float* __restrict__ mgA, const float* __restrict__ sgA,
                                                const int* __restrict__ mask_g,
                                                float* __restrict__ partL,
                                                float* __restrict__ partG){
  __shared__ __align__(16) float a_t[2][32][36];
  __shared__ __align__(16) float p_t[2][32][36];
  __shared__ __align__(16) float b_s[2][32][68];
  int i0 = blockIdx.x*32, h = blockIdx.y, s = blockIdx.z, j0 = s*128;
  int t = threadIdx.x;
  int il = t & 31, jq = t >> 5;          // staging: one i, four j per sub-tile
  int gi = h*N + i0 + il;
  float ml_r = mlA[gi], il_r = islA[gi];
  float mo_r = moA[gi], io_r = isoA[gi];
  float ma_r = maA[gi], ia_r = isaA[gi];
  float ng_r = ngA[gi];
  float mg_r = mgA[gi], isg_r = 1.f/sgA[gi];
  int   mgf_r = mask_g[gi];
  int fq = t & 15, iq = t >> 4;
  int jb2a = t>>4, d4a = t&15;
  int idxb = t + 256, jb2b = idxb>>4, d4b = idxb&15;

  float e0,e1,e2,e3; unsigned aw; float4 nf4, vb0, vb1;
  // prologue: load sub 0
  {
    int jb = j0;
    size_t ebase = ((size_t)h*N + jb + jq*4)*(size_t)N + i0 + il;
    e0 = eT[ebase]; e1 = eT[ebase+N]; e2 = eT[ebase+2*N]; e3 = eT[ebase+3*N];
    aw = adjbit[(size_t)(i0+il)*32 + s*4 + 0];
    nf4 = *(const float4*)(nf + jb + jq*4);
    vb0 = *(const float4*)(g_r + (size_t)(jb+jb2a)*256 + h*64 + d4a*4);
    vb1 = *(const float4*)(g_r + (size_t)(jb+jb2b)*256 + h*64 + d4b*4);
  }
  // compute + write buf 0
  {
    const float inv = 1.f/1024.f;
    float evs[4] = {e0,e1,e2,e3};
    float nfsv[4] = {nf4.x,nf4.y,nf4.z,nf4.w};
#pragma unroll
    for(int c=0;c<4;c++){
      int jl = jq*4 + c;                 // j local within 32-tile == bit index
      float a = ((aw >> jl) & 1u) ? __expf(evs[c]-ml_r)*il_r : 0.f;
      float omega = __expf(evs[c]-mo_r)*io_r;
      float alpha = __expf(fabsf(nfsv[c]-ng_r)-ma_r)*ia_r;
      float g = 0.5f*(omega + 1.f - alpha);
      float p = mgf_r ? __expf((g-mg_r)/1e-3f)*isg_r : inv;
      a_t[0][jl][il] = a;
      p_t[0][jl][il] = p;
    }
    *(float4*)&b_s[0][jb2a][d4a*4] = vb0;
    *(float4*)&b_s[0][jb2b][d4b*4] = vb1;
  }
  float4 accL[2], accG[2];
#pragma unroll
  for(int r=0;r<2;r++){ accL[r]=make_float4(0,0,0,0); accG[r]=make_float4(0,0,0,0); }

  for(int sub=0; sub<4; sub++){
    int cur = sub & 1;
    __syncthreads();                       // buf[cur] ready; buf[1-cur] free
    if(sub < 3){                           // issue next tile's loads (overlap compute)
      int jb = j0 + (sub+1)*32;
      size_t ebase = ((size_t)h*N + jb + jq*4)*(size_t)N + i0 + il;
      e0 = eT[ebase]; e1 = eT[ebase+N]; e2 = eT[ebase+2*N]; e3 = eT[ebase+3*N];
      aw = adjbit[(size_t)(i0+il)*32 + s*4 + sub + 1];
      nf4 = *(const float4*)(nf + jb + jq*4);
      vb0 = *(const float4*)(g_r + (size_t)(jb+jb2a)*256 + h*64 + d4a*4);
      vb1 = *(const float4*)(g_r + (size_t)(jb+jb2b)*256 + h*64 + d4b*4);
    }
#pragma unroll 8
    for(int j=0;j<32;j++){
      float4 bv = *(float4*)&b_s[cur][j][fq*4];
      float2 av = *(float2*)&a_t[cur][j][iq*2];
      float2 pv = *(float2*)&p_t[cur][j][iq*2];
      accL[0].x = fmaf(av.x, bv.x, accL[0].x); accL[0].y = fmaf(av.x, bv.y, accL[0].y);
      accL[0].z = fmaf(av.x, bv.z, accL[0].z); accL[0].w = fmaf(av.x, bv.w, accL[0].w);
      accL[1].x = fmaf(av.y, bv.x, accL[1].x); accL[1].y = fmaf(av.y, bv.y, accL[1].y);
      accL[1].z = fmaf(av.y, bv.z, accL[1].z); accL[1].w = fmaf(av.y, bv.w, accL[1].w);
      accG[0].x = fmaf(pv.x, bv.x, accG[0].x); accG[0].y = fmaf(pv.x, bv.y, accG[0].y);
      accG[0].z = fmaf(pv.x, bv.z, accG[0].z); accG[0].w = fmaf(pv.x, bv.w, accG[0].w);
      accG[1].x = fmaf(pv.y, bv.x, accG[1].x); accG[1].y = fmaf(pv.y, bv.y, accG[1].y);
      accG[1].z = fmaf(pv.y, bv.z, accG[1].z); accG[1].w = fmaf(pv.y, bv.w, accG[1].w);
    }
    if(sub < 3){                           // write next buffer (barrier above ensures free)
      int nxt = 1 - cur;
      const float inv = 1.f/1024.f;
      float evs[4] = {e0,e1,e2,e3};
      float nfsv[4] = {nf4.x,nf4.y,nf4.z,nf4.w};
#pragma unroll
      for(int c=0;c<4;c++){
        int jl = jq*4 + c;
        float a = ((aw >> jl) & 1u) ? __expf(evs[c]-ml_r)*il_r : 0.f;
        float omega = __expf(evs[c]-mo_r)*io_r;
        float alpha = __expf(fabsf(nfsv[c]-ng_r)-ma_r)*ia_r;
        float g = 0.5f*(omega + 1.f - alpha);
        float p = mgf_r ? __expf((g-mg_r)/1e-3f)*isg_r : inv;
        a_t[nxt][jl][il] = a;
        p_t[nxt][jl][il] = p;
      }
      *(float4*)&b_s[nxt][jb2a][d4a*4] = vb0;
      *(float4*)&b_s[nxt][jb2b][d4b*4] = vb1;
    }
  }
#pragma unroll
  for(int r=0;r<2;r++){
    int i = i0 + iq*2 + r;
    size_t o = ((size_t)s*N + i)*256 + h*64 + fq*4;
    *(float4*)&partL[o] = accL[r];
    *(float4*)&partG[o] = accG[r];
  }
}

// ---------------- K7: reduce partials + delta-gate epilogue ----------------
__global__ __launch_bounds__(256) void epilogue(const float* __restrict__ partL,
                                                const float* __restrict__ partG,
                                                const int* __restrict__ mask_l,
                                                const float* __restrict__ W_delta,
                                                const float* __restrict__ b_delta,
                                                float* __restrict__ out){
  __shared__ float cat[4][128];
  __shared__ float inter_s[4][64];
  int i = blockIdx.x, t = threadIdx.x;
  int h = t>>6, f = t&63;
  float sl = 0.f, sg = 0.f;
#pragma unroll
  for(int s2=0;s2<8;s2++){
    size_t o = ((size_t)s2*N + i)*256 + h*64 + f;
    sl += partL[o];
    sg += partG[o];
  }
  if(!mask_l[h*N + i]) sl = 0.f;
  cat[h][f]      = sl;
  cat[h][64 + f] = sg;
  __syncthreads();
  float d = b_delta[f];
  for(int c=0;c<128;c++) d = fmaf(cat[h][c], W_delta[(size_t)c*64 + f], d);
  d = (d >= 0.f) ? d : 0.2f*d;
  inter_s[h][f] = d;
  __syncthreads();
  float m = inter_s[0][f];
#pragma unroll
  for(int hh=1;hh<4;hh++) m = fmaxf(m, inter_s[hh][f]);
  float ssum = 0.f;
#pragma unroll
  for(int hh=0;hh<4;hh++) ssum += __expf(inter_s[hh][f]-m);
  float delta = __expf(d - m)/ssum;
  out[(size_t)i*256 + h*64 + f] = delta*sl + (1.f - delta)*sg;
}

// ---------------- launch ----------------
extern "C" void kernel_launch(void* const* d_in, const int* in_sizes, int n_in,
                              void* d_out, int out_size, void* d_ws, size_t ws_size,
                              hipStream_t stream) {
  const float* feats  = (const float*)d_in[0];
  const float* x      = (const float*)d_in[1];
  const int*   adj    = (const int*)  d_in[2];
  const float* W_l    = (const float*)d_in[3];
  const float* W_r    = (const float*)d_in[4];
  const float* attn_w = (const float*)d_in[5];
  const float* W_delta= (const float*)d_in[6];
  const float* b_delta= (const float*)d_in[7];
  float* out = (float*)d_out;

  float* ws = (float*)d_ws;
  size_t off = 0;
  float* g_l   = ws+off; off += (size_t)N*256;
  float* g_r   = ws+off; off += (size_t)N*256;
  float* e     = ws+off; off += (size_t)HN*N*N;      // raw scores, row-major
  float* eT    = ws+off; off += (size_t)HN*N*N;      // raw scores, transposed
  float* partL = ws+off; off += (size_t)8*N*256;     // per-s partials
  float* partG = ws+off; off += (size_t)8*N*256;
  float* pmin_f= ws+off; off += 16*128;
  float* pmax_f= ws+off; off += 16*128;
  float* pmin_g= ws+off; off += 16*256;
  float* pmax_g= ws+off; off += 16*256;
  float* nf    = ws+off; off += N;
  float* ng    = ws+off; off += (size_t)HN*N;
  float* mlA   = ws+off; off += (size_t)HN*N;
  float* islA  = ws+off; off += (size_t)HN*N;
  float* moA   = ws+off; off += (size_t)HN*N;
  float* isoA  = ws+off; off += (size_t)HN*N;
  float* maA   = ws+off; off += (size_t)HN*N;
  float* isaA  = ws+off; off += (size_t)HN*N;
  float* mgA   = ws+off; off += (size_t)HN*N;
  float* sgA   = ws+off; off += (size_t)HN*N;
  int* mask_l  = (int*)(ws+off); off += (size_t)HN*N;   // mask_l & mask_g contiguous
  int* mask_g  = (int*)(ws+off); off += (size_t)HN*N;
  unsigned* adjbit = (unsigned*)(ws+off); off += (size_t)N*32;

  stage1<<<1552, 256, 0, stream>>>(x, W_l, W_r, adj, feats, g_l, g_r, adjbit, mask_l, pmin_f, pmax_f);

  stage2<<<2064, 256, 0, stream>>>(g_l, g_r, attn_w, feats, pmin_f, pmax_f,
                                   pmin_g, pmax_g, nf, e, eT);

  row_stats<<<N, 256, 0, stream>>>(e, adjbit, nf, g_r, pmin_g, pmax_g, ng,
                                   mlA, islA, moA, isoA, maA, isaA, mgA, sgA);

  colselect9<<<2048, 256, 0, stream>>>(eT, adjbit, nf, mlA, islA, moA, isoA,
                                       maA, isaA, ng, mask_l, mask_g);

  attn_mm2<<<dim3(32,HN,8), 256, 0, stream>>>(eT, g_r, adjbit, nf,
                                              mlA, islA, moA, isoA, maA, isaA, ng,
                                              mgA, sgA, mask_g, partL, partG);

  epilogue<<<N, 256, 0, stream>>>(partL, partG, mask_l, W_delta, b_delta, out);
}

// Round 5
// 181.121 us; speedup vs baseline: 1.1039x; 1.0708x over previous
//
#include <hip/hip_runtime.h>
#include <cstdint>
#include <cstddef>

#define N 1024
#define HN 4
#define FDIM 64
#define KSEL 512
#define FLT_MAX_ 3.402823466e+38f

// ---------------- reduction helpers ----------------
__device__ __forceinline__ float wred_sum(float v){
#pragma unroll
  for(int o=32;o>0;o>>=1) v += __shfl_down(v,o,64);
  return v;
}
__device__ __forceinline__ float bfly_sum(float v){
#pragma unroll
  for(int o=1;o<64;o<<=1) v += __shfl_xor(v,o,64);
  return v;
}
__device__ __forceinline__ float bfly_max(float v){
#pragma unroll
  for(int o=1;o<64;o<<=1) v = fmaxf(v,__shfl_xor(v,o,64));
  return v;
}
__device__ __forceinline__ float bred_sum(float v, float* scr){
  int t=threadIdx.x;
  v = wred_sum(v);
  __syncthreads();
  if((t&63)==0) scr[t>>6]=v;
  __syncthreads();
  return (scr[0]+scr[1])+(scr[2]+scr[3]);
}

// ---------------- K1: fused gemm + pack_adj + mask zero + feats min/max ----------
__global__ __launch_bounds__(256) void stage1(const float* __restrict__ x,
                                              const float* __restrict__ W_l,
                                              const float* __restrict__ W_r,
                                              const int* __restrict__ adj,
                                              const float* __restrict__ feats,
                                              float* __restrict__ g_l,
                                              float* __restrict__ g_r,
                                              unsigned* __restrict__ adjbit,
                                              int* __restrict__ masks,
                                              float* __restrict__ pmin_f,
                                              float* __restrict__ pmax_f){
  int bx = blockIdx.x, t = threadIdx.x;
  if(bx < 512){
    const float* __restrict__ W = (bx >= 256) ? W_r : W_l;
    float* __restrict__ g = (bx >= 256) ? g_r : g_l;
    int i0 = (bx & 255)*4;
    float acc[4] = {0.f,0.f,0.f,0.f};
#pragma unroll 8
    for(int k=0;k<256;k++){
      float w = W[(size_t)k*256 + t];
#pragma unroll
      for(int r=0;r<4;r++) acc[r] = fmaf(x[(size_t)(i0+r)*256 + k], w, acc[r]);
    }
#pragma unroll
    for(int r=0;r<4;r++) g[(size_t)(i0+r)*256 + t] = acc[r];
  } else if(bx < 1536){
    int i = bx - 512, w = t>>6, lane = t&63;
    if(i < 32) masks[i*256 + t] = 0;
#pragma unroll
    for(int it=0; it<4; it++){
      int j = w*256 + it*64 + lane;
      int v = adj[(size_t)i*N + j];
      unsigned long long mb = __ballot(v > 0);
      if(lane == 0){
        adjbit[i*32 + w*8 + it*2]     = (unsigned)mb;
        adjbit[i*32 + w*8 + it*2 + 1] = (unsigned)(mb >> 32);
      }
    }
  } else {
    int chunk = bx - 1536;
    if(t < 128){
      float lo = FLT_MAX_, hi = -FLT_MAX_;
      int r0 = chunk*64;
      for(int r=0;r<64;r++){
        float v = feats[(size_t)(r0+r)*128 + t];
        lo = fminf(lo,v); hi = fmaxf(hi,v);
      }
      pmin_f[chunk*128+t]=lo; pmax_f[chunk*128+t]=hi;
    }
  }
}

// ---------------- K2: fused compute_e (+eT transpose) + g_r min/max/sum + nf -----
__global__ __launch_bounds__(256) void stage2(const float* __restrict__ g_l,
                                              const float* __restrict__ g_r,
                                              const float* __restrict__ attn_w,
                                              const float* __restrict__ feats,
                                              const float* __restrict__ pmin_f, const float* __restrict__ pmax_f,
                                              float* __restrict__ pmin_g, float* __restrict__ pmax_g,
                                              float* __restrict__ psum_g,
                                              float* __restrict__ nf,
                                              float* __restrict__ e,
                                              float* __restrict__ eT){
  __shared__ __align__(16) float smem[2*64*68 + 128];
  int bx = blockIdx.x, t = threadIdx.x;
  if(bx < 1024){
    float* grs = smem;                 // [64][68]
    float* gls = smem + 64*68;         // [64][68]
    float* aw  = smem + 2*64*68;       // [64]
    float* aw2 = aw + 64;              // [64]
    int h = bx >> 8, i0 = ((bx>>4)&15)*64, j0 = (bx&15)*64;
    if(t < 64){ float w = attn_w[t]; aw[t]=w; aw2[t]=0.2f*w; }
#pragma unroll
    for(int k=0;k<16;k++){
      int idx = t + k*256; int r = idx>>6, f = idx&63;
      grs[r*68+f] = g_r[(size_t)(i0+r)*256 + h*64 + f];
      gls[r*68+f] = g_l[(size_t)(j0+r)*256 + h*64 + f];
    }
    __syncthreads();
    int tj = t&15, ti = t>>4;
    float acc[4][4];
#pragma unroll
    for(int a=0;a<4;a++)
#pragma unroll
      for(int b=0;b<4;b++) acc[a][b]=0.f;
    for(int fc=0; fc<64; fc+=4){
      float4 wv  = *(float4*)&aw[fc];
      float4 wv2 = *(float4*)&aw2[fc];
      float4 ga4[4], gb4[4];
#pragma unroll
      for(int a=0;a<4;a++) ga4[a] = *(float4*)&grs[(ti*4+a)*68+fc];
#pragma unroll
      for(int b=0;b<4;b++) gb4[b] = *(float4*)&gls[(tj+16*b)*68+fc];
#pragma unroll
      for(int a=0;a<4;a++)
#pragma unroll
        for(int b=0;b<4;b++){
          float s0 = ga4[a].x + gb4[b].x;
          float s1 = ga4[a].y + gb4[b].y;
          float s2 = ga4[a].z + gb4[b].z;
          float s3 = ga4[a].w + gb4[b].w;
          acc[a][b] = fmaf(s0, (s0>=0.f)?wv.x:wv2.x, acc[a][b]);
          acc[a][b] = fmaf(s1, (s1>=0.f)?wv.y:wv2.y, acc[a][b]);
          acc[a][b] = fmaf(s2, (s2>=0.f)?wv.z:wv2.z, acc[a][b]);
          acc[a][b] = fmaf(s3, (s3>=0.f)?wv.w:wv2.w, acc[a][b]);
        }
    }
#pragma unroll
    for(int a=0;a<4;a++)
#pragma unroll
      for(int b=0;b<4;b++){
        int i = i0 + ti*4 + a, j = j0 + tj + 16*b;
        e[((size_t)h*N + i)*N + j] = acc[a][b];
      }
    // transposed copy eT[h][j][i] via LDS (reuse grs/gls region)
    __syncthreads();                        // all reads of grs/gls done
    float* esT = smem;                      // [64][68]
#pragma unroll
    for(int a=0;a<4;a++)
#pragma unroll
      for(int b=0;b<4;b++)
        esT[(tj + 16*b)*68 + ti*4 + a] = acc[a][b];
    __syncthreads();
#pragma unroll
    for(int k=0;k<4;k++){
      int jl = (t>>4) + 16*k, ilx = (t&15)*4;
      *(float4*)(eT + ((size_t)h*N + j0 + jl)*N + i0 + ilx) = *(float4*)&esT[jl*68 + ilx];
    }
  } else if(bx < 1040){
    int chunk = bx - 1024;
    float lo = FLT_MAX_, hi = -FLT_MAX_, sm = 0.f;
    int r0 = chunk*64;
    for(int r=0;r<64;r++){
      float v = g_r[(size_t)(r0+r)*256 + t];
      lo = fminf(lo,v); hi = fmaxf(hi,v); sm += v;
    }
    pmin_g[chunk*256+t]=lo; pmax_g[chunk*256+t]=hi; psum_g[chunk*256+t]=sm;
  } else {
    int i = bx - 1040;
    float* scr = smem;
    float u = 0.f;
    if(t < 128){
      float lo = FLT_MAX_, hi = -FLT_MAX_;
#pragma unroll
      for(int k=0;k<16;k++){
        lo = fminf(lo, pmin_f[k*128+t]);
        hi = fmaxf(hi, pmax_f[k*128+t]);
      }
      float d = hi - lo;
      float v = feats[(size_t)i*128 + t];
      u = (d==0.f) ? 0.f : (v - lo)/d;
    }
    float tot = bred_sum(u*u, scr);
    if(t==0) nf[i] = sqrtf(tot);
  }
}

// ---------------- K3: row stats — wave/(h,row), inline ng, zero barriers ----------
__global__ __launch_bounds__(256) void row_stats(const float* __restrict__ e,
                                                 const unsigned* __restrict__ adjbit,
                                                 const float* __restrict__ nf,
                                                 const float* __restrict__ g_r,
                                                 const float* __restrict__ pmin_g, const float* __restrict__ pmax_g,
                                                 float* __restrict__ ng,
                                                 float* __restrict__ mlA, float* __restrict__ islA,
                                                 float* __restrict__ moA, float* __restrict__ isoA,
                                                 float* __restrict__ maA, float* __restrict__ isaA,
                                                 float* __restrict__ mgA, float* __restrict__ sgA){
  int i = blockIdx.x, t = threadIdx.x, h = t>>6, lane = t&63;
  float glo = FLT_MAX_, ghi = -FLT_MAX_;
#pragma unroll
  for(int k=0;k<16;k++){
    glo = fminf(glo, pmin_g[k*256 + h*64 + lane]);
    ghi = fmaxf(ghi, pmax_g[k*256 + h*64 + lane]);
  }
  float dg = ghi - glo;
  float ug = (g_r[(size_t)i*256 + h*64 + lane] - glo)/dg;   // no guard (matches ref)
  float ngv = sqrtf(bfly_sum(ug*ug));
  if(lane==0) ng[h*N + i] = ngv;

  size_t base = ((size_t)h*N + i)*N;
  float er[16], nfr[16];
  unsigned nib[4];
#pragma unroll
  for(int c=0;c<4;c++){
    float4 e4 = *(const float4*)(e  + base + c*256 + lane*4);
    float4 n4 = *(const float4*)(nf + c*256 + lane*4);
    er[c*4+0]=e4.x; er[c*4+1]=e4.y; er[c*4+2]=e4.z; er[c*4+3]=e4.w;
    nfr[c*4+0]=n4.x; nfr[c*4+1]=n4.y; nfr[c*4+2]=n4.z; nfr[c*4+3]=n4.w;
    nib[c] = (adjbit[i*32 + c*8 + (lane>>3)] >> ((lane&7)*4)) & 0xFu;
  }
  float ml=-FLT_MAX_, mo=-FLT_MAX_, ma=-FLT_MAX_;
#pragma unroll
  for(int c=0;c<4;c++)
#pragma unroll
    for(int k=0;k<4;k++){
      int q = c*4+k;
      float ev = er[q];
      mo = fmaxf(mo, ev);
      if((nib[c]>>k)&1) ml = fmaxf(ml, ev);
      ma = fmaxf(ma, fabsf(nfr[q]-ngv));
    }
  ml = bfly_max(ml); mo = bfly_max(mo); ma = bfly_max(ma);
  float sl=0.f, so=0.f, sa=0.f;
#pragma unroll
  for(int c=0;c<4;c++)
#pragma unroll
    for(int k=0;k<4;k++){
      int q = c*4+k;
      float ev = er[q];
      so += __expf(ev-mo);
      if((nib[c]>>k)&1) sl += __expf(ev-ml);
      sa += __expf(fabsf(nfr[q]-ngv)-ma);
    }
  sl = bfly_sum(sl); so = bfly_sum(so); sa = bfly_sum(sa);
  float isl = 1.f/sl, iso = 1.f/so, isa = 1.f/sa;
  float gg[16];
  float mg = -FLT_MAX_;
#pragma unroll
  for(int q=0;q<16;q++){
    float ev = er[q];
    float omega = __expf(ev-mo)*iso;
    float alpha = __expf(fabsf(nfr[q]-ngv)-ma)*isa;
    float g = 0.5f*(omega + 1.f - alpha);
    gg[q] = g;
    mg = fmaxf(mg, g);
  }
  mg = bfly_max(mg);
  float sg = 0.f;
#pragma unroll
  for(int q=0;q<16;q++) sg += __expf((gg[q]-mg)/1e-3f);
  sg = bfly_sum(sg);
  if(lane==0){
    mlA[h*N+i]=ml; islA[h*N+i]=isl;
    moA[h*N+i]=mo; isoA[h*N+i]=iso;
    maA[h*N+i]=ma; isaA[h*N+i]=isa;
    mgA[h*N+i]=mg; sgA[h*N+i]=sg;
  }
}

// ---------------- mask application with exact tie semantics (index order) --------
__device__ __forceinline__ void apply_mask(const unsigned* ur, unsigned T, int tneed, int EQ,
                                           int* __restrict__ mask, int base, int lane){
  if(EQ == tneed){
#pragma unroll
    for(int c=0;c<4;c++)
#pragma unroll
      for(int k2=0;k2<4;k2++){
        int i = c*256 + lane*4 + k2;
        if(ur[c*4+k2] >= T) mask[base + i] = 1;
      }
  } else {
    int run_base = 0;
#pragma unroll
    for(int c=0;c<4;c++){
      unsigned long long bm[4];
#pragma unroll
      for(int k2=0;k2<4;k2++) bm[k2] = __ballot(ur[c*4+k2]==T);
      unsigned long long lower = (lane==0) ? 0ull : (~0ull >> (64-lane));
      int run = run_base;
#pragma unroll
      for(int k2=0;k2<4;k2++) run += (int)__popcll(bm[k2] & lower);
#pragma unroll
      for(int k2=0;k2<4;k2++){
        int i = c*256 + lane*4 + k2;
        unsigned u = ur[c*4+k2];
        bool sel = (u > T) || (u == T && run < tneed);
        run += (u==T)?1:0;
        if(sel) mask[base + i] = 1;
      }
      int ctot = 0;
#pragma unroll
      for(int k2=0;k2<4;k2++) ctot += (int)__popcll(bm[k2]);
      run_base += ctot;
    }
  }
}

// ---------------- K4: fused attn matmuls + dual top-512 select -------------------
// grid (96, HN, 8): bx<32 -> mm tile (i0=bx*32, h, j0=s*128);
//                   bx>=32 -> select block sid=(bx-32)+64*(h+4*s) in [0,2048),
//                            4 waves x 1 column each (gcol=sid*4+w in [0,8192)).
// Select is independent of mm (partG computed unconditionally; mask_g applied in
// the epilogue via the uniform-fallback identity attn_global = colsum(g_r)/N).
__global__ __launch_bounds__(256) void mm_sel(const float* __restrict__ eT,
                                              const float* __restrict__ g_r,
                                              const unsigned* __restrict__ adjbit,
                                              const float* __restrict__ nf,
                                              const float* __restrict__ mlA, const float* __restrict__ islA,
                                              const float* __restrict__ moA, const float* __restrict__ isoA,
                                              const float* __restrict__ maA, const float* __restrict__ isaA,
                                              const float* __restrict__ ngA,
                                              const float* __restrict__ mgA, const float* __restrict__ sgA,
                                              float* __restrict__ partL,
                                              float* __restrict__ partG,
                                              int* __restrict__ mask_l,
                                              int* __restrict__ mask_g){
  __shared__ __align__(16) float a_t[2][32][36];
  __shared__ __align__(16) float p_t[2][32][36];
  __shared__ __align__(16) float b_s[2][32][68];
  int bx = blockIdx.x, h = blockIdx.y, s = blockIdx.z;
  int t = threadIdx.x;

  if(bx >= 32){
    // ---------------- select path (register-only, no barriers) ----------------
    int w = t>>6, lane = t&63;
    int sid = (bx - 32) + 64*(h + 4*s);
    int gcol = sid*4 + w;                 // 0..8191
    int z  = gcol >> 12;                  // 0: a1 select, 1: gamma select
    int hj = gcol & 4095;
    int hh = hj >> 10, jc = hj & 1023;
    const float* __restrict__ src = eT + (size_t)hj * (size_t)N;

    float ev[16];
#pragma unroll
    for(int c=0;c<4;c++){
      float4 e4 = ((const float4*)src)[c*64 + lane];
      ev[c*4+0]=e4.x; ev[c*4+1]=e4.y; ev[c*4+2]=e4.z; ev[c*4+3]=e4.w;
    }
    unsigned ur[16];
    if(z == 0){
      int wo = jc >> 5; unsigned bm = 1u << (jc & 31);
#pragma unroll
      for(int c=0;c<4;c++){
        int ib = (hh<<10) + c*256 + lane*4;
        float4 ml4 = *(const float4*)(mlA+ib);
        float4 il4 = *(const float4*)(islA+ib);
        float mlv[4] = {ml4.x,ml4.y,ml4.z,ml4.w};
        float ilv[4] = {il4.x,il4.y,il4.z,il4.w};
#pragma unroll
        for(int k=0;k<4;k++){
          int i = c*256 + lane*4 + k;
          float a = (adjbit[i*32 + wo] & bm) ? __expf(ev[c*4+k]-mlv[k])*ilv[k] : 0.f;
          ur[c*4+k] = __float_as_uint(a);
        }
      }
    } else {
      float nfv = nf[jc];
#pragma unroll
      for(int c=0;c<4;c++){
        int ib = (hh<<10) + c*256 + lane*4;
        float4 mo4 = *(const float4*)(moA+ib);
        float4 io4 = *(const float4*)(isoA+ib);
        float4 ma4 = *(const float4*)(maA+ib);
        float4 ia4 = *(const float4*)(isaA+ib);
        float4 ng4 = *(const float4*)(ngA+ib);
        float mov[4]={mo4.x,mo4.y,mo4.z,mo4.w}, iov[4]={io4.x,io4.y,io4.z,io4.w};
        float mav[4]={ma4.x,ma4.y,ma4.z,ma4.w}, iav[4]={ia4.x,ia4.y,ia4.z,ia4.w};
        float ngv[4]={ng4.x,ng4.y,ng4.z,ng4.w};
#pragma unroll
        for(int k=0;k<4;k++){
          float omega = __expf(ev[c*4+k]-mov[k])*iov[k];
          float alpha = __expf(fabsf(nfv-ngv[k])-mav[k])*iav[k];
          float g = 0.5f*(omega + 1.f - alpha);
          ur[c*4+k] = __float_as_uint(g);
        }
      }
    }

    // bitwise kth-largest; wave count = sum of ballot popcounts.
    unsigned prefix = 0u;
    for(int b=30; b>=0; b--){
      unsigned cand = prefix | (1u<<b);
      int c = 0;
#pragma unroll
      for(int q=0;q<16;q++) c += (int)__popcll(__ballot(ur[q] >= cand));
      prefix = (c >= KSEL) ? cand : prefix;
    }
    unsigned T = prefix;
    int GT = 0, EQ = 0;
#pragma unroll
    for(int q=0;q<16;q++){
      GT += (int)__popcll(__ballot(ur[q] > T));
      EQ += (int)__popcll(__ballot(ur[q] == T));
    }
    int tneed = KSEL - GT;

    int* __restrict__ mask = z ? mask_g : mask_l;
    apply_mask(ur, T, tneed, EQ, mask, hh<<10, lane);
    return;
  }

  // ---------------- mm path (stats in registers; no mask_g dependency) ----------
  int i0 = bx*32, j0 = s*128;
  int il = t & 31, jq = t >> 5;          // staging: one i, four j per sub-tile
  int gi = h*N + i0 + il;
  float ml_r = mlA[gi], il_r = islA[gi];
  float mo_r = moA[gi], io_r = isoA[gi];
  float ma_r = maA[gi], ia_r = isaA[gi];
  float ng_r = ngA[gi];
  float mg_r = mgA[gi], isg_r = 1.f/sgA[gi];
  int fq = t & 15, iq = t >> 4;
  int jb2a = t>>4, d4a = t&15;
  int idxb = t + 256, jb2b = idxb>>4, d4b = idxb&15;

  float e0,e1,e2,e3; unsigned aw; float4 nf4, vb0, vb1;
  // prologue: load sub 0
  {
    int jb = j0;
    size_t ebase = ((size_t)h*N + jb + jq*4)*(size_t)N + i0 + il;
    e0 = eT[ebase]; e1 = eT[ebase+N]; e2 = eT[ebase+2*N]; e3 = eT[ebase+3*N];
    aw = adjbit[(size_t)(i0+il)*32 + s*4 + 0];
    nf4 = *(const float4*)(nf + jb + jq*4);
    vb0 = *(const float4*)(g_r + (size_t)(jb+jb2a)*256 + h*64 + d4a*4);
    vb1 = *(const float4*)(g_r + (size_t)(jb+jb2b)*256 + h*64 + d4b*4);
  }
  // compute + write buf 0
  {
    float evs[4] = {e0,e1,e2,e3};
    float nfsv[4] = {nf4.x,nf4.y,nf4.z,nf4.w};
#pragma unroll
    for(int c=0;c<4;c++){
      int jl = jq*4 + c;                 // j local within 32-tile == bit index
      float a = ((aw >> jl) & 1u) ? __expf(evs[c]-ml_r)*il_r : 0.f;
      float omega = __expf(evs[c]-mo_r)*io_r;
      float alpha = __expf(fabsf(nfsv[c]-ng_r)-ma_r)*ia_r;
      float g = 0.5f*(omega + 1.f - alpha);
      float p = __expf((g-mg_r)/1e-3f)*isg_r;
      a_t[0][jl][il] = a;
      p_t[0][jl][il] = p;
    }
    *(float4*)&b_s[0][jb2a][d4a*4] = vb0;
    *(float4*)&b_s[0][jb2b][d4b*4] = vb1;
  }
  float4 accL[2], accG[2];
#pragma unroll
  for(int r=0;r<2;r++){ accL[r]=make_float4(0,0,0,0); accG[r]=make_float4(0,0,0,0); }

  for(int sub=0; sub<4; sub++){
    int cur = sub & 1;
    __syncthreads();                       // buf[cur] ready; buf[1-cur] free
    if(sub < 3){                           // issue next tile's loads (overlap compute)
      int jb = j0 + (sub+1)*32;
      size_t ebase = ((size_t)h*N + jb + jq*4)*(size_t)N + i0 + il;
      e0 = eT[ebase]; e1 = eT[ebase+N]; e2 = eT[ebase+2*N]; e3 = eT[ebase+3*N];
      aw = adjbit[(size_t)(i0+il)*32 + s*4 + sub + 1];
      nf4 = *(const float4*)(nf + jb + jq*4);
      vb0 = *(const float4*)(g_r + (size_t)(jb+jb2a)*256 + h*64 + d4a*4);
      vb1 = *(const float4*)(g_r + (size_t)(jb+jb2b)*256 + h*64 + d4b*4);
    }
#pragma unroll 8
    for(int j=0;j<32;j++){
      float4 bv = *(float4*)&b_s[cur][j][fq*4];
      float2 av = *(float2*)&a_t[cur][j][iq*2];
      float2 pv = *(float2*)&p_t[cur][j][iq*2];
      accL[0].x = fmaf(av.x, bv.x, accL[0].x); accL[0].y = fmaf(av.x, bv.y, accL[0].y);
      accL[0].z = fmaf(av.x, bv.z, accL[0].z); accL[0].w = fmaf(av.x, bv.w, accL[0].w);
      accL[1].x = fmaf(av.y, bv.x, accL[1].x); accL[1].y = fmaf(av.y, bv.y, accL[1].y);
      accL[1].z = fmaf(av.y, bv.z, accL[1].z); accL[1].w = fmaf(av.y, bv.w, accL[1].w);
      accG[0].x = fmaf(pv.x, bv.x, accG[0].x); accG[0].y = fmaf(pv.x, bv.y, accG[0].y);
      accG[0].z = fmaf(pv.x, bv.z, accG[0].z); accG[0].w = fmaf(pv.x, bv.w, accG[0].w);
      accG[1].x = fmaf(pv.y, bv.x, accG[1].x); accG[1].y = fmaf(pv.y, bv.y, accG[1].y);
      accG[1].z = fmaf(pv.y, bv.z, accG[1].z); accG[1].w = fmaf(pv.y, bv.w, accG[1].w);
    }
    if(sub < 3){                           // write next buffer (barrier above ensures free)
      int nxt = 1 - cur;
      float evs[4] = {e0,e1,e2,e3};
      float nfsv[4] = {nf4.x,nf4.y,nf4.z,nf4.w};
#pragma unroll
      for(int c=0;c<4;c++){
        int jl = jq*4 + c;
        float a = ((aw >> jl) & 1u) ? __expf(evs[c]-ml_r)*il_r : 0.f;
        float omega = __expf(evs[c]-mo_r)*io_r;
        float alpha = __expf(fabsf(nfsv[c]-ng_r)-ma_r)*ia_r;
        float g = 0.5f*(omega + 1.f - alpha);
        float p = __expf((g-mg_r)/1e-3f)*isg_r;
        a_t[nxt][jl][il] = a;
        p_t[nxt][jl][il] = p;
      }
      *(float4*)&b_s[nxt][jb2a][d4a*4] = vb0;
      *(float4*)&b_s[nxt][jb2b][d4b*4] = vb1;
    }
  }
#pragma unroll
  for(int r=0;r<2;r++){
    int i = i0 + iq*2 + r;
    size_t o = ((size_t)s*N + i)*256 + h*64 + fq*4;
    *(float4*)&partL[o] = accL[r];
    *(float4*)&partG[o] = accG[r];
  }
}

// ---------------- K5: reduce partials + mask fallbacks + delta-gate epilogue -----
__global__ __launch_bounds__(256) void epilogue(const float* __restrict__ partL,
                                                const float* __restrict__ partG,
                                                const int* __restrict__ mask_l,
                                                const int* __restrict__ mask_g,
                                                const float* __restrict__ psum_g,
                                                const float* __restrict__ W_delta,
                                                const float* __restrict__ b_delta,
                                                float* __restrict__ out){
  __shared__ float cat[4][128];
  __shared__ float inter_s[4][64];
  int i = blockIdx.x, t = threadIdx.x;
  int h = t>>6, f = t&63;
  float sl = 0.f, sg = 0.f;
#pragma unroll
  for(int s2=0;s2<8;s2++){
    size_t o = ((size_t)s2*N + i)*256 + h*64 + f;
    sl += partL[o];
    sg += partG[o];
  }
  if(!mask_l[h*N + i]) sl = 0.f;
  if(!mask_g[h*N + i]){
    // uniform-fallback rows: attn_global = colsum(g_r)/N
    float gs = 0.f;
#pragma unroll
    for(int k=0;k<16;k++) gs += psum_g[k*256 + t];
    sg = gs * (1.f/1024.f);
  }
  cat[h][f]      = sl;
  cat[h][64 + f] = sg;
  __syncthreads();
  float d = b_delta[f];
  for(int c=0;c<128;c++) d = fmaf(cat[h][c], W_delta[(size_t)c*64 + f], d);
  d = (d >= 0.f) ? d : 0.2f*d;
  inter_s[h][f] = d;
  __syncthreads();
  float m = inter_s[0][f];
#pragma unroll
  for(int hh=1;hh<4;hh++) m = fmaxf(m, inter_s[hh][f]);
  float ssum = 0.f;
#pragma unroll
  for(int hh=0;hh<4;hh++) ssum += __expf(inter_s[hh][f]-m);
  float delta = __expf(d - m)/ssum;
  out[(size_t)i*256 + h*64 + f] = delta*sl + (1.f - delta)*sg;
}

// ---------------- launch ----------------
extern "C" void kernel_launch(void* const* d_in, const int* in_sizes, int n_in,
                              void* d_out, int out_size, void* d_ws, size_t ws_size,
                              hipStream_t stream) {
  const float* feats  = (const float*)d_in[0];
  const float* x      = (const float*)d_in[1];
  const int*   adj    = (const int*)  d_in[2];
  const float* W_l    = (const float*)d_in[3];
  const float* W_r    = (const float*)d_in[4];
  const float* attn_w = (const float*)d_in[5];
  const float* W_delta= (const float*)d_in[6];
  const float* b_delta= (const float*)d_in[7];
  float* out = (float*)d_out;

  float* ws = (float*)d_ws;
  size_t off = 0;
  float* g_l   = ws+off; off += (size_t)N*256;
  float* g_r   = ws+off; off += (size_t)N*256;
  float* e     = ws+off; off += (size_t)HN*N*N;      // raw scores, row-major
  float* eT    = ws+off; off += (size_t)HN*N*N;      // raw scores, transposed
  float* partL = ws+off; off += (size_t)8*N*256;     // per-s partials
  float* partG = ws+off; off += (size_t)8*N*256;
  float* pmin_f= ws+off; off += 16*128;
  float* pmax_f= ws+off; off += 16*128;
  float* pmin_g= ws+off; off += 16*256;
  float* pmax_g= ws+off; off += 16*256;
  float* psum_g= ws+off; off += 16*256;
  float* nf    = ws+off; off += N;
  float* ng    = ws+off; off += (size_t)HN*N;
  float* mlA   = ws+off; off += (size_t)HN*N;
  float* islA  = ws+off; off += (size_t)HN*N;
  float* moA   = ws+off; off += (size_t)HN*N;
  float* isoA  = ws+off; off += (size_t)HN*N;
  float* maA   = ws+off; off += (size_t)HN*N;
  float* isaA  = ws+off; off += (size_t)HN*N;
  float* mgA   = ws+off; off += (size_t)HN*N;
  float* sgA   = ws+off; off += (size_t)HN*N;
  int* mask_l  = (int*)(ws+off); off += (size_t)HN*N;   // mask_l & mask_g contiguous
  int* mask_g  = (int*)(ws+off); off += (size_t)HN*N;
  unsigned* adjbit = (unsigned*)(ws+off); off += (size_t)N*32;

  stage1<<<1552, 256, 0, stream>>>(x, W_l, W_r, adj, feats, g_l, g_r, adjbit, mask_l, pmin_f, pmax_f);

  stage2<<<2064, 256, 0, stream>>>(g_l, g_r, attn_w, feats, pmin_f, pmax_f,
                                   pmin_g, pmax_g, psum_g, nf, e, eT);

  row_stats<<<N, 256, 0, stream>>>(e, adjbit, nf, g_r, pmin_g, pmax_g, ng,
                                   mlA, islA, moA, isoA, maA, isaA, mgA, sgA);

  mm_sel<<<dim3(96,HN,8), 256, 0, stream>>>(eT, g_r, adjbit, nf,
                                            mlA, islA, moA, isoA, maA, isaA, ng,
                                            mgA, sgA, partL, partG, mask_l, mask_g);

  epilogue<<<N, 256, 0, stream>>>(partL, partG, mask_l, mask_g, psum_g, W_delta, b_delta, out);
}